// Round 4
// baseline (431.433 us; speedup 1.0000x reference)
//
#include <hip/hip_runtime.h>
#include <math.h>

#define BB 64
#define TT 512
#define DD 256
#define CC 20
#define SS 32          // segments
#define LL 16          // steps per segment
#define PR 20          // prob row stride (floats); 80B rows, float4-aligned
#define LN_EPS 1e-5f

// ws layout (floats)
// probs: BB*TT*PR              = 655,360 floats (2.62 MB)
// Pbuf : BB*SS*CC*CC           = 819,200 floats (3.28 MB), column-major per segment
// scale: BB*SS                 = 2,048
// nll  : BB

__device__ __forceinline__ float dpp_sum16(float v) {
  v += __int_as_float(__builtin_amdgcn_update_dpp(0, __float_as_int(v), 0xB1, 0xF, 0xF, true));
  v += __int_as_float(__builtin_amdgcn_update_dpp(0, __float_as_int(v), 0x4E, 0xF, 0xF, true));
  v += __int_as_float(__builtin_amdgcn_update_dpp(0, __float_as_int(v), 0x141, 0xF, 0xF, true));
  v += __int_as_float(__builtin_amdgcn_update_dpp(0, __float_as_int(v), 0x140, 0xF, 0xF, true));
  return v;
}
__device__ __forceinline__ float wave_reduce_sum64(float v) {
  #pragma unroll
  for (int off = 32; off > 0; off >>= 1) v += __shfl_xor(v, off, 64);
  return v;
}

// ---- Kernel A: emb gather + LN + linear + softmax probs (fp32). ----
// 16 lanes/token, 64 tokens per 256-thread block, grid 512. No atomics.
__global__ __launch_bounds__(256) void token_probs_kernel(
    const int* __restrict__ words, const float* __restrict__ emb,
    const float* __restrict__ ln_g, const float* __restrict__ ln_b,
    const float* __restrict__ W, const float* __restrict__ bias,
    float* __restrict__ probs)
{
  __shared__ __align__(16) float4 sW4[64 * 21];  // [d4][c], stride 21
  __shared__ float sb[CC];
  int tid = threadIdx.x;
  for (int ei = tid; ei < 64 * CC; ei += 256) {
    int d4 = ei / CC, c = ei - d4 * CC;
    int base = 4 * d4 * CC + c;  // W is (D, C) row-major
    sW4[d4 * 21 + c] = make_float4(W[base], W[base + CC], W[base + 2 * CC], W[base + 3 * CC]);
  }
  if (tid < CC) sb[tid] = bias[tid];
  __syncthreads();

  int lane = tid & 63, wave = tid >> 6;
  int sub = lane >> 4, l = lane & 15;

  float4 g4[4], b4[4];
  #pragma unroll
  for (int q = 0; q < 4; ++q) {
    g4[q] = ((const float4*)ln_g)[l + 16 * q];
    b4[q] = ((const float4*)ln_b)[l + 16 * q];
  }

  for (int gidx = 0; gidx < 4; ++gidx) {
    int token = blockIdx.x * 64 + wave * 16 + gidx * 4 + sub;
    int word = words[token];
    const float4* row = (const float4*)(emb + (size_t)word * DD);
    float4 x4[4];
    #pragma unroll
    for (int q = 0; q < 4; ++q) x4[q] = row[l + 16 * q];

    float s1 = 0.f, s2 = 0.f;
    #pragma unroll
    for (int q = 0; q < 4; ++q) {
      s1 += (x4[q].x + x4[q].y) + (x4[q].z + x4[q].w);
      s2 += (x4[q].x * x4[q].x + x4[q].y * x4[q].y) + (x4[q].z * x4[q].z + x4[q].w * x4[q].w);
    }
    s1 = dpp_sum16(s1);
    s2 = dpp_sum16(s2);
    float mu = s1 * (1.f / DD);
    float var = s2 * (1.f / DD) - mu * mu;
    float rr = rsqrtf(var + LN_EPS);

    float4 xn[4];
    #pragma unroll
    for (int q = 0; q < 4; ++q) {
      xn[q].x = (x4[q].x - mu) * rr * g4[q].x + b4[q].x;
      xn[q].y = (x4[q].y - mu) * rr * g4[q].y + b4[q].y;
      xn[q].z = (x4[q].z - mu) * rr * g4[q].z + b4[q].z;
      xn[q].w = (x4[q].w - mu) * rr * g4[q].w + b4[q].w;
    }

    float p[CC];
    #pragma unroll
    for (int c = 0; c < CC; ++c) p[c] = 0.f;
    #pragma unroll
    for (int q = 0; q < 4; ++q) {
      const float4* wrow = &sW4[(l + 16 * q) * 21];
      #pragma unroll
      for (int c = 0; c < CC; ++c) {
        float4 w = wrow[c];
        p[c] += (xn[q].x * w.x + xn[q].y * w.y) + (xn[q].z * w.z + xn[q].w * w.w);
      }
    }

    float feats[CC];
    #pragma unroll
    for (int c = 0; c < CC; ++c) feats[c] = dpp_sum16(p[c]) + sb[c];

    float m = feats[0];
    #pragma unroll
    for (int c = 1; c < CC; ++c) m = fmaxf(m, feats[c]);
    float ev[CC];
    float ssum = 0.f;
    #pragma unroll
    for (int c = 0; c < CC; ++c) { ev[c] = __expf(feats[c] - m); ssum += ev[c]; }
    float inv = 1.0f / ssum;

    // lane l<5 stores float4 (4l..4l+3) — constant-index select tree, no scratch
    float4 o = make_float4(0.f, 0.f, 0.f, 0.f);
    #pragma unroll
    for (int mm = 0; mm < 5; ++mm) {
      if (l == mm)
        o = make_float4(ev[4 * mm] * inv, ev[4 * mm + 1] * inv,
                        ev[4 * mm + 2] * inv, ev[4 * mm + 3] * inv);
    }
    if (l < 5) ((float4*)(probs + (size_t)token * PR))[l] = o;
  }
}

// ---- Kernel A2: per-segment 20x20 product matrices, thread-per-column, fp32. ----
// chain: v <- diag(pr_t) E^T v, start e_k. E = exp(trans) in LDS (broadcast reads).
__global__ __launch_bounds__(320) void segment_kernel(
    const float* __restrict__ probs, const int* __restrict__ seq_len,
    const float* __restrict__ trans,
    float* __restrict__ Pbuf, float* __restrict__ scaleBuf)
{
  __shared__ __align__(16) float sE[CC * CC];
  __shared__ float smass[16 * CC];
  int tid = threadIdx.x;
  for (int ei = tid; ei < CC * CC; ei += 320) sE[ei] = __expf(trans[ei]);
  __syncthreads();

  int g_local = tid / CC, k = tid - g_local * CC;
  int g = blockIdx.x * 16 + g_local;   // g = b*SS + s
  int b = g >> 5, s = g & (SS - 1);
  int len = seq_len[b];

  float v[CC];
  #pragma unroll
  for (int c = 0; c < CC; ++c) v[c] = (c == k) ? 1.f : 0.f;

  int t0 = s * LL + 1;
  int tend = min(s * LL + LL, len - 1);
  for (int t = t0; t <= tend; ++t) {
    const float4* prp = (const float4*)(probs + ((size_t)b * TT + t) * PR);
    float4 P0 = prp[0], P1 = prp[1], P2 = prp[2], P3 = prp[3], P4 = prp[4];
    float pr[CC] = {P0.x, P0.y, P0.z, P0.w, P1.x, P1.y, P1.z, P1.w,
                    P2.x, P2.y, P2.z, P2.w, P3.x, P3.y, P3.z, P3.w,
                    P4.x, P4.y, P4.z, P4.w};
    float out[CC];
    #pragma unroll
    for (int j = 0; j < CC; ++j) out[j] = 0.f;
    #pragma unroll
    for (int i = 0; i < CC; ++i) {
      float vi = v[i];
      const float4* er = (const float4*)(sE + i * CC);
      float4 e0 = er[0], e1 = er[1], e2 = er[2], e3 = er[3], e4 = er[4];
      out[0] += e0.x * vi;  out[1] += e0.y * vi;  out[2] += e0.z * vi;  out[3] += e0.w * vi;
      out[4] += e1.x * vi;  out[5] += e1.y * vi;  out[6] += e1.z * vi;  out[7] += e1.w * vi;
      out[8] += e2.x * vi;  out[9] += e2.y * vi;  out[10] += e2.z * vi; out[11] += e2.w * vi;
      out[12] += e3.x * vi; out[13] += e3.y * vi; out[14] += e3.z * vi; out[15] += e3.w * vi;
      out[16] += e4.x * vi; out[17] += e4.y * vi; out[18] += e4.z * vi; out[19] += e4.w * vi;
    }
    #pragma unroll
    for (int j = 0; j < CC; ++j) v[j] = out[j] * pr[j];
  }

  float mass = 0.f;
  #pragma unroll
  for (int j = 0; j < CC; ++j) mass += v[j];
  smass[g_local * CC + k] = mass;
  __syncthreads();
  float mx = 0.f;
  #pragma unroll
  for (int i = 0; i < CC; ++i) mx = fmaxf(mx, smass[g_local * CC + i]);
  float sc = 1.0f / mx;

  float4* col = (float4*)(Pbuf + ((size_t)g * CC + k) * CC);  // column k contiguous
  #pragma unroll
  for (int r = 0; r < 5; ++r)
    col[r] = make_float4(v[4 * r] * sc, v[4 * r + 1] * sc,
                         v[4 * r + 2] * sc, v[4 * r + 3] * sc);
  if (k == 0) scaleBuf[g] = __logf(mx);
}

// ---- Kernel B: gold score (lane-parallel) + serial 32-segment combine. ----
__global__ __launch_bounds__(64) void combine_kernel(
    const float* __restrict__ probs, const float* __restrict__ Pbuf,
    const float* __restrict__ scaleBuf, const int* __restrict__ seq_len,
    const int* __restrict__ target, const float* __restrict__ trans,
    const float* __restrict__ startv, const float* __restrict__ endv,
    float* __restrict__ nll)
{
  int b = blockIdx.x;
  int j = threadIdx.x;
  int len = seq_len[b];
  const float* pb = probs + (size_t)b * TT * PR;
  const int* tg = target + b * TT;

  // gold score, lanes parallel over t (log(prob) == feats - lsm up to ulp)
  float gsum = 0.f;
  for (int t = j; t < len; t += 64) {
    int cur = tg[t];
    gsum += __logf(pb[(size_t)t * PR + cur]);
    if (t >= 1) gsum += trans[tg[t - 1] * CC + cur];
  }
  gsum = wave_reduce_sum64(gsum);

  // replicated serial combine (no cross-lane in chain)
  const float4* prp = (const float4*)pb;
  float4 P0 = prp[0], P1 = prp[1], P2 = prp[2], P3 = prp[3], P4 = prp[4];
  float p0[CC] = {P0.x, P0.y, P0.z, P0.w, P1.x, P1.y, P1.z, P1.w,
                  P2.x, P2.y, P2.z, P2.w, P3.x, P3.y, P3.z, P3.w,
                  P4.x, P4.y, P4.z, P4.w};
  float a[CC];
  float mass0 = 0.f;
  #pragma unroll
  for (int c = 0; c < CC; ++c) { a[c] = p0[c] * __expf(startv[c]); mass0 += a[c]; }
  float Z = __logf(mass0);
  float inv0 = 1.0f / mass0;
  #pragma unroll
  for (int c = 0; c < CC; ++c) a[c] *= inv0;

  for (int s = 0; s < SS; ++s) {
    const float* base = Pbuf + (size_t)(b * SS + s) * CC * CC;
    float out[CC];
    #pragma unroll
    for (int c = 0; c < CC; ++c) out[c] = 0.f;
    #pragma unroll
    for (int i = 0; i < CC; ++i) {
      float ai = a[i];
      const float4* cp = (const float4*)(base + i * CC);  // column i of M_s
      float4 c0 = cp[0], c1 = cp[1], c2 = cp[2], c3 = cp[3], c4 = cp[4];
      out[0] += c0.x * ai;  out[1] += c0.y * ai;  out[2] += c0.z * ai;  out[3] += c0.w * ai;
      out[4] += c1.x * ai;  out[5] += c1.y * ai;  out[6] += c1.z * ai;  out[7] += c1.w * ai;
      out[8] += c2.x * ai;  out[9] += c2.y * ai;  out[10] += c2.z * ai; out[11] += c2.w * ai;
      out[12] += c3.x * ai; out[13] += c3.y * ai; out[14] += c3.z * ai; out[15] += c3.w * ai;
      out[16] += c4.x * ai; out[17] += c4.y * ai; out[18] += c4.z * ai; out[19] += c4.w * ai;
    }
    float mass = 0.f;
    #pragma unroll
    for (int c = 0; c < CC; ++c) mass += out[c];
    Z += __logf(mass) + scaleBuf[b * SS + s];
    float minv = 1.0f / mass;
    #pragma unroll
    for (int c = 0; c < CC; ++c) a[c] = out[c] * minv;
  }

  float sacc = 0.f;
  #pragma unroll
  for (int c = 0; c < CC; ++c) sacc += a[c] * __expf(endv[c]);
  float norm = Z + __logf(sacc);

  if (j == 0) {
    float gold = gsum + startv[tg[0]] + endv[tg[len - 1]];
    nll[b] = norm - gold;
  }
}

// ---- Kernel C: mean over B ----
__global__ __launch_bounds__(64) void mean_kernel(
    const float* __restrict__ nll, float* __restrict__ out)
{
  float v = nll[threadIdx.x];
  v = wave_reduce_sum64(v);
  if (threadIdx.x == 0) out[0] = v * (1.0f / BB);
}

extern "C" void kernel_launch(void* const* d_in, const int* in_sizes, int n_in,
                              void* d_out, int out_size, void* d_ws, size_t ws_size,
                              hipStream_t stream) {
  const int*   words   = (const int*)d_in[0];
  const int*   seq_len = (const int*)d_in[1];
  const int*   target  = (const int*)d_in[2];
  const float* emb     = (const float*)d_in[3];
  const float* ln_g    = (const float*)d_in[4];
  const float* ln_b    = (const float*)d_in[5];
  const float* W       = (const float*)d_in[6];
  const float* bias    = (const float*)d_in[7];
  const float* trans   = (const float*)d_in[8];
  const float* startv  = (const float*)d_in[9];
  const float* endv    = (const float*)d_in[10];

  float* probs    = (float*)d_ws;                          // 655,360
  float* Pbuf     = probs + (size_t)BB * TT * PR;          // 819,200
  float* scaleBuf = Pbuf + (size_t)BB * SS * CC * CC;      // 2,048
  float* nll      = scaleBuf + (size_t)BB * SS;            // 64
  float* out      = (float*)d_out;

  token_probs_kernel<<<512, 256, 0, stream>>>(words, emb, ln_g, ln_b, W, bias,
                                              probs);
  segment_kernel<<<128, 320, 0, stream>>>(probs, seq_len, trans, Pbuf, scaleBuf);
  combine_kernel<<<BB, 64, 0, stream>>>(probs, Pbuf, scaleBuf, seq_len, target,
                                        trans, startv, endv, nll);
  mean_kernel<<<1, 64, 0, stream>>>(nll, out);
}

// Round 5
// 386.167 us; speedup vs baseline: 1.1172x; 1.1172x over previous
//
#include <hip/hip_runtime.h>
#include <math.h>

#define BB 64
#define TT 512
#define DD 256
#define CC 20
#define SS 32          // segments
#define LL 16          // steps per segment
#define PR 20          // prob row stride (floats)
#define NG (BB * SS)   // 2048 segment chains
#define LN_EPS 1e-5f

__device__ __forceinline__ float dpp_sum16(float v) {
  v += __int_as_float(__builtin_amdgcn_update_dpp(0, __float_as_int(v), 0xB1, 0xF, 0xF, true));
  v += __int_as_float(__builtin_amdgcn_update_dpp(0, __float_as_int(v), 0x4E, 0xF, 0xF, true));
  v += __int_as_float(__builtin_amdgcn_update_dpp(0, __float_as_int(v), 0x141, 0xF, 0xF, true));
  v += __int_as_float(__builtin_amdgcn_update_dpp(0, __float_as_int(v), 0x140, 0xF, 0xF, true));
  return v;
}
__device__ __forceinline__ float wave_reduce_sum64(float v) {
  #pragma unroll
  for (int off = 32; off > 0; off >>= 1) v += __shfl_xor(v, off, 64);
  return v;
}

// ---- Kernel 0: precompute exp(trans) once ----
__global__ __launch_bounds__(512) void init_expE_kernel(
    const float* __restrict__ trans, float* __restrict__ expE)
{
  int i = threadIdx.x;
  if (i < CC * CC) expE[i] = __expf(trans[i]);
}

// ---- Kernel A: emb gather + LN + linear + softmax probs (fp32). ----
// 16 lanes/token, 64 tokens per 256-thread block, grid 512.
__global__ __launch_bounds__(256) void token_probs_kernel(
    const int* __restrict__ words, const float* __restrict__ emb,
    const float* __restrict__ ln_g, const float* __restrict__ ln_b,
    const float* __restrict__ W, const float* __restrict__ bias,
    float* __restrict__ probs)
{
  __shared__ __align__(16) float4 sW4[64 * 21];  // [d4][c], stride 21
  __shared__ float sb[CC];
  int tid = threadIdx.x;
  for (int ei = tid; ei < 64 * CC; ei += 256) {
    int d4 = ei / CC, c = ei - d4 * CC;
    int base = 4 * d4 * CC + c;  // W is (D, C) row-major
    sW4[d4 * 21 + c] = make_float4(W[base], W[base + CC], W[base + 2 * CC], W[base + 3 * CC]);
  }
  if (tid < CC) sb[tid] = bias[tid];
  __syncthreads();

  int lane = tid & 63, wave = tid >> 6;
  int sub = lane >> 4, l = lane & 15;

  float4 g4[4], b4[4];
  #pragma unroll
  for (int q = 0; q < 4; ++q) {
    g4[q] = ((const float4*)ln_g)[l + 16 * q];
    b4[q] = ((const float4*)ln_b)[l + 16 * q];
  }

  for (int gidx = 0; gidx < 4; ++gidx) {
    int token = blockIdx.x * 64 + wave * 16 + gidx * 4 + sub;
    int word = words[token];
    const float4* row = (const float4*)(emb + (size_t)word * DD);
    float4 x4[4];
    #pragma unroll
    for (int q = 0; q < 4; ++q) x4[q] = row[l + 16 * q];

    float s1 = 0.f, s2 = 0.f;
    #pragma unroll
    for (int q = 0; q < 4; ++q) {
      s1 += (x4[q].x + x4[q].y) + (x4[q].z + x4[q].w);
      s2 += (x4[q].x * x4[q].x + x4[q].y * x4[q].y) + (x4[q].z * x4[q].z + x4[q].w * x4[q].w);
    }
    s1 = dpp_sum16(s1);
    s2 = dpp_sum16(s2);
    float mu = s1 * (1.f / DD);
    float var = s2 * (1.f / DD) - mu * mu;
    float rr = rsqrtf(var + LN_EPS);

    float4 xn[4];
    #pragma unroll
    for (int q = 0; q < 4; ++q) {
      xn[q].x = (x4[q].x - mu) * rr * g4[q].x + b4[q].x;
      xn[q].y = (x4[q].y - mu) * rr * g4[q].y + b4[q].y;
      xn[q].z = (x4[q].z - mu) * rr * g4[q].z + b4[q].z;
      xn[q].w = (x4[q].w - mu) * rr * g4[q].w + b4[q].w;
    }

    float p[CC];
    #pragma unroll
    for (int c = 0; c < CC; ++c) p[c] = 0.f;
    #pragma unroll
    for (int q = 0; q < 4; ++q) {
      const float4* wrow = &sW4[(l + 16 * q) * 21];
      #pragma unroll
      for (int c = 0; c < CC; ++c) {
        float4 w = wrow[c];
        p[c] += (xn[q].x * w.x + xn[q].y * w.y) + (xn[q].z * w.z + xn[q].w * w.w);
      }
    }

    float feats[CC];
    #pragma unroll
    for (int c = 0; c < CC; ++c) feats[c] = dpp_sum16(p[c]) + sb[c];

    float m = feats[0];
    #pragma unroll
    for (int c = 1; c < CC; ++c) m = fmaxf(m, feats[c]);
    float ev[CC];
    float ssum = 0.f;
    #pragma unroll
    for (int c = 0; c < CC; ++c) { ev[c] = __expf(feats[c] - m); ssum += ev[c]; }
    float inv = 1.0f / ssum;

    float4 o = make_float4(0.f, 0.f, 0.f, 0.f);
    #pragma unroll
    for (int mm = 0; mm < 5; ++mm) {
      if (l == mm)
        o = make_float4(ev[4 * mm] * inv, ev[4 * mm + 1] * inv,
                        ev[4 * mm + 2] * inv, ev[4 * mm + 3] * inv);
    }
    if (l < 5) ((float4*)(probs + (size_t)token * PR))[l] = o;
  }
}

// ---- Kernel A2: per-segment 20x20 product matrices, thread-per-column. ----
// 64-thread blocks (1 wave) = 3 groups of 20 threads; launch_bounds(64,2) ->
// 256-VGPR cap, chain state stays in registers (the R4 version spilled at 128).
__global__ __launch_bounds__(64, 2) void segment_kernel(
    const float* __restrict__ probs, const int* __restrict__ seq_len,
    const float* __restrict__ expE,
    float* __restrict__ Pbuf, float* __restrict__ scaleBuf)
{
  __shared__ __align__(16) float sE[CC * CC];
  __shared__ float smass[3 * CC];
  int tid = threadIdx.x;
  for (int ei = tid; ei < CC * CC; ei += 64) sE[ei] = expE[ei];
  __syncthreads();

  int grp = tid / CC;               // 0..2 active, 3 = idle lanes 60..63
  int k = tid - grp * CC;
  bool active = tid < 60;
  int g = blockIdx.x * 3 + (active ? grp : 0);
  if (g >= NG) { g = NG - 1; active = false; }
  int b = g >> 5, s = g & (SS - 1);
  int len = seq_len[b];

  float v[CC];
  #pragma unroll
  for (int c = 0; c < CC; ++c) v[c] = (c == k) ? 1.f : 0.f;

  int t0 = s * LL + 1;
  int tend = min(s * LL + LL, len - 1);
  const float* pbase = probs + (size_t)b * TT * PR;
  for (int t = t0; t <= tend; ++t) {
    const float4* prp = (const float4*)(pbase + (size_t)t * PR);
    float4 P0 = prp[0], P1 = prp[1], P2 = prp[2], P3 = prp[3], P4 = prp[4];
    float w[CC];
    #pragma unroll
    for (int j = 0; j < CC; ++j) w[j] = 0.f;
    #pragma unroll
    for (int i = 0; i < CC; ++i) {
      float vi = v[i];
      const float4* er = (const float4*)(sE + i * CC);
      float4 e0 = er[0], e1 = er[1], e2 = er[2], e3 = er[3], e4 = er[4];
      w[0] += e0.x * vi;  w[1] += e0.y * vi;  w[2] += e0.z * vi;  w[3] += e0.w * vi;
      w[4] += e1.x * vi;  w[5] += e1.y * vi;  w[6] += e1.z * vi;  w[7] += e1.w * vi;
      w[8] += e2.x * vi;  w[9] += e2.y * vi;  w[10] += e2.z * vi; w[11] += e2.w * vi;
      w[12] += e3.x * vi; w[13] += e3.y * vi; w[14] += e3.z * vi; w[15] += e3.w * vi;
      w[16] += e4.x * vi; w[17] += e4.y * vi; w[18] += e4.z * vi; w[19] += e4.w * vi;
    }
    v[0] = w[0] * P0.x;   v[1] = w[1] * P0.y;   v[2] = w[2] * P0.z;   v[3] = w[3] * P0.w;
    v[4] = w[4] * P1.x;   v[5] = w[5] * P1.y;   v[6] = w[6] * P1.z;   v[7] = w[7] * P1.w;
    v[8] = w[8] * P2.x;   v[9] = w[9] * P2.y;   v[10] = w[10] * P2.z; v[11] = w[11] * P2.w;
    v[12] = w[12] * P3.x; v[13] = w[13] * P3.y; v[14] = w[14] * P3.z; v[15] = w[15] * P3.w;
    v[16] = w[16] * P4.x; v[17] = w[17] * P4.y; v[18] = w[18] * P4.z; v[19] = w[19] * P4.w;
  }

  float mass = 0.f;
  #pragma unroll
  for (int j = 0; j < CC; ++j) mass += v[j];
  if (active) smass[grp * CC + k] = mass;
  __syncthreads();
  if (active) {
    float mx = 0.f;
    #pragma unroll
    for (int i = 0; i < CC; ++i) mx = fmaxf(mx, smass[grp * CC + i]);
    float sc = 1.0f / mx;
    float4* col = (float4*)(Pbuf + ((size_t)g * CC + k) * CC);
    #pragma unroll
    for (int r = 0; r < 5; ++r)
      col[r] = make_float4(v[4 * r] * sc, v[4 * r + 1] * sc,
                           v[4 * r + 2] * sc, v[4 * r + 3] * sc);
    if (k == 0) scaleBuf[g] = __logf(mx);
  }
}

// ---- Kernel B: gold score (lane-parallel) + serial 32-segment combine. ----
__global__ __launch_bounds__(64, 2) void combine_kernel(
    const float* __restrict__ probs, const float* __restrict__ Pbuf,
    const float* __restrict__ scaleBuf, const int* __restrict__ seq_len,
    const int* __restrict__ target, const float* __restrict__ trans,
    const float* __restrict__ startv, const float* __restrict__ endv,
    float* __restrict__ nll)
{
  int b = blockIdx.x;
  int j = threadIdx.x;
  int len = seq_len[b];
  const float* pb = probs + (size_t)b * TT * PR;
  const int* tg = target + b * TT;

  float gsum = 0.f;
  for (int t = j; t < len; t += 64) {
    int cur = tg[t];
    gsum += __logf(pb[(size_t)t * PR + cur]);
    if (t >= 1) gsum += trans[tg[t - 1] * CC + cur];
  }
  gsum = wave_reduce_sum64(gsum);

  const float4* prp = (const float4*)pb;
  float4 P0 = prp[0], P1 = prp[1], P2 = prp[2], P3 = prp[3], P4 = prp[4];
  float p0[CC] = {P0.x, P0.y, P0.z, P0.w, P1.x, P1.y, P1.z, P1.w,
                  P2.x, P2.y, P2.z, P2.w, P3.x, P3.y, P3.z, P3.w,
                  P4.x, P4.y, P4.z, P4.w};
  float a[CC];
  float mass0 = 0.f;
  #pragma unroll
  for (int c = 0; c < CC; ++c) { a[c] = p0[c] * __expf(startv[c]); mass0 += a[c]; }
  float Z = __logf(mass0);
  float inv0 = 1.0f / mass0;
  #pragma unroll
  for (int c = 0; c < CC; ++c) a[c] *= inv0;

  for (int s = 0; s < SS; ++s) {
    const float* base = Pbuf + (size_t)(b * SS + s) * CC * CC;
    float out[CC];
    #pragma unroll
    for (int c = 0; c < CC; ++c) out[c] = 0.f;
    #pragma unroll
    for (int i = 0; i < CC; ++i) {
      float ai = a[i];
      const float4* cp = (const float4*)(base + i * CC);  // column i of M_s
      float4 c0 = cp[0], c1 = cp[1], c2 = cp[2], c3 = cp[3], c4 = cp[4];
      out[0] += c0.x * ai;  out[1] += c0.y * ai;  out[2] += c0.z * ai;  out[3] += c0.w * ai;
      out[4] += c1.x * ai;  out[5] += c1.y * ai;  out[6] += c1.z * ai;  out[7] += c1.w * ai;
      out[8] += c2.x * ai;  out[9] += c2.y * ai;  out[10] += c2.z * ai; out[11] += c2.w * ai;
      out[12] += c3.x * ai; out[13] += c3.y * ai; out[14] += c3.z * ai; out[15] += c3.w * ai;
      out[16] += c4.x * ai; out[17] += c4.y * ai; out[18] += c4.z * ai; out[19] += c4.w * ai;
    }
    float mass = 0.f;
    #pragma unroll
    for (int c = 0; c < CC; ++c) mass += out[c];
    Z += __logf(mass) + scaleBuf[b * SS + s];
    float minv = 1.0f / mass;
    #pragma unroll
    for (int c = 0; c < CC; ++c) a[c] = out[c] * minv;
  }

  float sacc = 0.f;
  #pragma unroll
  for (int c = 0; c < CC; ++c) sacc += a[c] * __expf(endv[c]);
  float norm = Z + __logf(sacc);

  if (j == 0) {
    float gold = gsum + startv[tg[0]] + endv[tg[len - 1]];
    nll[b] = norm - gold;
  }
}

// ---- Kernel C: mean over B ----
__global__ __launch_bounds__(64) void mean_kernel(
    const float* __restrict__ nll, float* __restrict__ out)
{
  float v = nll[threadIdx.x];
  v = wave_reduce_sum64(v);
  if (threadIdx.x == 0) out[0] = v * (1.0f / BB);
}

extern "C" void kernel_launch(void* const* d_in, const int* in_sizes, int n_in,
                              void* d_out, int out_size, void* d_ws, size_t ws_size,
                              hipStream_t stream) {
  const int*   words   = (const int*)d_in[0];
  const int*   seq_len = (const int*)d_in[1];
  const int*   target  = (const int*)d_in[2];
  const float* emb     = (const float*)d_in[3];
  const float* ln_g    = (const float*)d_in[4];
  const float* ln_b    = (const float*)d_in[5];
  const float* W       = (const float*)d_in[6];
  const float* bias    = (const float*)d_in[7];
  const float* trans   = (const float*)d_in[8];
  const float* startv  = (const float*)d_in[9];
  const float* endv    = (const float*)d_in[10];

  float* probs    = (float*)d_ws;                          // 655,360 floats
  float* Pbuf     = probs + (size_t)BB * TT * PR;          // 819,200
  float* scaleBuf = Pbuf + (size_t)BB * SS * CC * CC;      // 2,048
  float* nll      = scaleBuf + (size_t)BB * SS;            // 64
  float* expE     = nll + BB;                              // 400
  float* out      = (float*)d_out;

  init_expE_kernel<<<1, 512, 0, stream>>>(trans, expE);
  token_probs_kernel<<<512, 256, 0, stream>>>(words, emb, ln_g, ln_b, W, bias,
                                              probs);
  segment_kernel<<<(NG + 2) / 3, 64, 0, stream>>>(probs, seq_len, expE, Pbuf,
                                                  scaleBuf);
  combine_kernel<<<BB, 64, 0, stream>>>(probs, Pbuf, scaleBuf, seq_len, target,
                                        trans, startv, endv, nll);
  mean_kernel<<<1, 64, 0, stream>>>(nll, out);
}

// Round 6
// 263.452 us; speedup vs baseline: 1.6376x; 1.4658x over previous
//
#include <hip/hip_runtime.h>
#include <math.h>

#define BB 64
#define TT 512
#define DD 256
#define CC 20
#define SS 32            // segments per batch element
#define LL 16            // steps per segment
#define PR 20            // prob row stride (floats)
#define NSEG (BB * SS)   // 2048 segments
#define NCH (NSEG * CC)  // 40960 column chains
#define LN_EPS 1e-5f

__device__ __forceinline__ float dpp_sum16(float v) {
  v += __int_as_float(__builtin_amdgcn_update_dpp(0, __float_as_int(v), 0xB1, 0xF, 0xF, true));
  v += __int_as_float(__builtin_amdgcn_update_dpp(0, __float_as_int(v), 0x4E, 0xF, 0xF, true));
  v += __int_as_float(__builtin_amdgcn_update_dpp(0, __float_as_int(v), 0x141, 0xF, 0xF, true));
  v += __int_as_float(__builtin_amdgcn_update_dpp(0, __float_as_int(v), 0x140, 0xF, 0xF, true));
  return v;
}
__device__ __forceinline__ float dpp_max16(float v) {
  v = fmaxf(v, __int_as_float(__builtin_amdgcn_update_dpp(0, __float_as_int(v), 0xB1, 0xF, 0xF, true)));
  v = fmaxf(v, __int_as_float(__builtin_amdgcn_update_dpp(0, __float_as_int(v), 0x4E, 0xF, 0xF, true)));
  v = fmaxf(v, __int_as_float(__builtin_amdgcn_update_dpp(0, __float_as_int(v), 0x141, 0xF, 0xF, true)));
  v = fmaxf(v, __int_as_float(__builtin_amdgcn_update_dpp(0, __float_as_int(v), 0x140, 0xF, 0xF, true)));
  return v;
}
__device__ __forceinline__ float wave_reduce_sum64(float v) {
  #pragma unroll
  for (int off = 32; off > 0; off >>= 1) v += __shfl_xor(v, off, 64);
  return v;
}
__device__ __forceinline__ float wave_reduce_max64(float v) {
  #pragma unroll
  for (int off = 32; off > 0; off >>= 1) v = fmaxf(v, __shfl_xor(v, off, 64));
  return v;
}

// ---- Kernel 0: precompute exp(trans) ----
__global__ __launch_bounds__(512) void init_expE_kernel(
    const float* __restrict__ trans, float* __restrict__ expE)
{
  int i = threadIdx.x;
  if (i < CC * CC) expE[i] = __expf(trans[i]);
}

// ---- Kernel A: emb gather + LN + linear + softmax probs. ----
// 16 lanes/token, 64 tokens per 256-thread block, grid 512.
// NO per-thread arrays: feats held as 1-2 scalars per lane via predicated keep.
__global__ __launch_bounds__(256, 1) void token_probs_kernel(
    const int* __restrict__ words, const float* __restrict__ emb,
    const float* __restrict__ ln_g, const float* __restrict__ ln_b,
    const float* __restrict__ W, const float* __restrict__ bias,
    float* __restrict__ probs)
{
  __shared__ __align__(16) float4 sW4[64 * 21];  // [d4][c], stride 21
  __shared__ float sb[CC];
  int tid = threadIdx.x;
  for (int ei = tid; ei < 64 * CC; ei += 256) {
    int d4 = ei / CC, c = ei - d4 * CC;
    int base = 4 * d4 * CC + c;  // W is (D, C) row-major
    sW4[d4 * 21 + c] = make_float4(W[base], W[base + CC], W[base + 2 * CC], W[base + 3 * CC]);
  }
  if (tid < CC) sb[tid] = bias[tid];
  __syncthreads();

  int lane = tid & 63, wave = tid >> 6;
  int sub = lane >> 4, l = lane & 15;

  float4 g0 = ((const float4*)ln_g)[l];
  float4 g1 = ((const float4*)ln_g)[l + 16];
  float4 g2 = ((const float4*)ln_g)[l + 32];
  float4 g3 = ((const float4*)ln_g)[l + 48];
  float4 e0v = ((const float4*)ln_b)[l];
  float4 e1v = ((const float4*)ln_b)[l + 16];
  float4 e2v = ((const float4*)ln_b)[l + 32];
  float4 e3v = ((const float4*)ln_b)[l + 48];

  for (int gidx = 0; gidx < 4; ++gidx) {
    int token = blockIdx.x * 64 + wave * 16 + gidx * 4 + sub;
    int word = words[token];
    const float4* row = (const float4*)(emb + (size_t)word * DD);
    float4 x0 = row[l], x1 = row[l + 16], x2 = row[l + 32], x3 = row[l + 48];

    float s1 = (x0.x + x0.y) + (x0.z + x0.w) + (x1.x + x1.y) + (x1.z + x1.w)
             + (x2.x + x2.y) + (x2.z + x2.w) + (x3.x + x3.y) + (x3.z + x3.w);
    float s2 = x0.x*x0.x + x0.y*x0.y + x0.z*x0.z + x0.w*x0.w
             + x1.x*x1.x + x1.y*x1.y + x1.z*x1.z + x1.w*x1.w
             + x2.x*x2.x + x2.y*x2.y + x2.z*x2.z + x2.w*x2.w
             + x3.x*x3.x + x3.y*x3.y + x3.z*x3.z + x3.w*x3.w;
    s1 = dpp_sum16(s1);
    s2 = dpp_sum16(s2);
    float mu = s1 * (1.f / DD);
    float var = s2 * (1.f / DD) - mu * mu;
    float rr = rsqrtf(var + LN_EPS);

    x0.x = (x0.x - mu) * rr * g0.x + e0v.x;  x0.y = (x0.y - mu) * rr * g0.y + e0v.y;
    x0.z = (x0.z - mu) * rr * g0.z + e0v.z;  x0.w = (x0.w - mu) * rr * g0.w + e0v.w;
    x1.x = (x1.x - mu) * rr * g1.x + e1v.x;  x1.y = (x1.y - mu) * rr * g1.y + e1v.y;
    x1.z = (x1.z - mu) * rr * g1.z + e1v.z;  x1.w = (x1.w - mu) * rr * g1.w + e1v.w;
    x2.x = (x2.x - mu) * rr * g2.x + e2v.x;  x2.y = (x2.y - mu) * rr * g2.y + e2v.y;
    x2.z = (x2.z - mu) * rr * g2.z + e2v.z;  x2.w = (x2.w - mu) * rr * g2.w + e2v.w;
    x3.x = (x3.x - mu) * rr * g3.x + e3v.x;  x3.y = (x3.y - mu) * rr * g3.y + e3v.y;
    x3.z = (x3.z - mu) * rr * g3.z + e3v.z;  x3.w = (x3.w - mu) * rr * g3.w + e3v.w;

    float f0 = 0.f, f1 = 0.f;  // lane l holds feat_l; lanes 0..3 also feat_{16+l}
    #pragma unroll
    for (int c = 0; c < CC; ++c) {
      float4 w0 = sW4[l * 21 + c];
      float4 w1 = sW4[(l + 16) * 21 + c];
      float4 w2 = sW4[(l + 32) * 21 + c];
      float4 w3 = sW4[(l + 48) * 21 + c];
      float pp = (x0.x*w0.x + x0.y*w0.y) + (x0.z*w0.z + x0.w*w0.w)
               + (x1.x*w1.x + x1.y*w1.y) + (x1.z*w1.z + x1.w*w1.w)
               + (x2.x*w2.x + x2.y*w2.y) + (x2.z*w2.z + x2.w*w2.w)
               + (x3.x*w3.x + x3.y*w3.y) + (x3.z*w3.z + x3.w*w3.w);
      pp = dpp_sum16(pp) + sb[c];
      if (c < 16) { if (l == c) f0 = pp; }
      else        { if (l == c - 16) f1 = pp; }
    }

    float m = f0;
    if (l < 4) m = fmaxf(m, f1);
    m = dpp_max16(m);
    float q0 = __expf(f0 - m);
    float q1 = (l < 4) ? __expf(f1 - m) : 0.f;
    float ssum = dpp_sum16(q0 + q1);
    float inv = 1.0f / ssum;

    float* pt = probs + (size_t)token * PR;
    pt[l] = q0 * inv;
    if (l < 4) pt[16 + l] = q1 * inv;
  }
}

// ---- Kernel A2: segment column chains, lane-distributed. ----
// Chain ch = g*20+k evolves column k of segment g: v <- diag(pr_t) E^T v.
// 20 lanes per chain (lane holds ONE scalar state + 20 E scalars), 3 chains
// per 64-thread block. Per-column normalization with log scale.
__global__ __launch_bounds__(64, 1) void segment_kernel(
    const float* __restrict__ probs, const int* __restrict__ seq_len,
    const float* __restrict__ expE,
    float* __restrict__ Pbuf, float* __restrict__ scaleBuf)
{
  int tid = threadIdx.x;
  int grp = tid / 20;           // 0..2 active, 3 idle
  int l = tid - grp * 20;
  int chain = blockIdx.x * 3 + grp;
  bool act = (grp < 3) && (chain < NCH);
  int ch = act ? chain : 0;
  int g = ch / 20, k = ch - g * 20;
  int b = g >> 5, s = g & (SS - 1);
  int len = seq_len[b];
  int base = act ? grp * 20 : 0;

  // E row per lane: E_i = exp(trans[i][l])
  float E0  = expE[0*CC + l],  E1  = expE[1*CC + l],  E2  = expE[2*CC + l],  E3  = expE[3*CC + l];
  float E4  = expE[4*CC + l],  E5  = expE[5*CC + l],  E6  = expE[6*CC + l],  E7  = expE[7*CC + l];
  float E8  = expE[8*CC + l],  E9  = expE[9*CC + l],  E10 = expE[10*CC + l], E11 = expE[11*CC + l];
  float E12 = expE[12*CC + l], E13 = expE[13*CC + l], E14 = expE[14*CC + l], E15 = expE[15*CC + l];
  float E16 = expE[16*CC + l], E17 = expE[17*CC + l], E18 = expE[18*CC + l], E19 = expE[19*CC + l];

  float v = (l == k) ? 1.f : 0.f;
  const float* pb = probs + (size_t)b * TT * PR + l;
  int t0 = s * LL + 1;
  int tend = min(s * LL + LL, len - 1);

  for (int t = t0; t <= tend; ++t) {
    float pr = pb[t * PR];
    float a0, a1, a2, a3;
    a0  = __shfl(v, base + 0, 64) * E0;
    a1  = __shfl(v, base + 1, 64) * E1;
    a2  = __shfl(v, base + 2, 64) * E2;
    a3  = __shfl(v, base + 3, 64) * E3;
    a0 += __shfl(v, base + 4, 64) * E4;
    a1 += __shfl(v, base + 5, 64) * E5;
    a2 += __shfl(v, base + 6, 64) * E6;
    a3 += __shfl(v, base + 7, 64) * E7;
    a0 += __shfl(v, base + 8, 64) * E8;
    a1 += __shfl(v, base + 9, 64) * E9;
    a2 += __shfl(v, base + 10, 64) * E10;
    a3 += __shfl(v, base + 11, 64) * E11;
    a0 += __shfl(v, base + 12, 64) * E12;
    a1 += __shfl(v, base + 13, 64) * E13;
    a2 += __shfl(v, base + 14, 64) * E14;
    a3 += __shfl(v, base + 15, 64) * E15;
    a0 += __shfl(v, base + 16, 64) * E16;
    a1 += __shfl(v, base + 17, 64) * E17;
    a2 += __shfl(v, base + 18, 64) * E18;
    a3 += __shfl(v, base + 19, 64) * E19;
    v = ((a0 + a1) + (a2 + a3)) * pr;
  }

  __shared__ float sv[64];
  sv[tid] = v;
  __syncthreads();
  float mass = 0.f;
  #pragma unroll
  for (int i = 0; i < CC; ++i) mass += sv[base + i];

  if (act) {
    if (mass > 1e-35f) {
      float inv = 1.0f / mass;
      Pbuf[(size_t)ch * CC + l] = v * inv;
      if (l == 0) scaleBuf[ch] = __logf(mass);
    } else {
      Pbuf[(size_t)ch * CC + l] = 0.f;
      if (l == 0) scaleBuf[ch] = -1e30f;
    }
  }
}

// ---- Kernel B: gold score + serial 32-segment combine (lane j holds a_j). ----
__global__ __launch_bounds__(64, 1) void combine_kernel(
    const float* __restrict__ probs, const float* __restrict__ Pbuf,
    const float* __restrict__ scaleBuf, const int* __restrict__ seq_len,
    const int* __restrict__ target, const float* __restrict__ trans,
    const float* __restrict__ startv, const float* __restrict__ endv,
    float* __restrict__ nll)
{
  int b = blockIdx.x;
  int j = threadIdx.x;
  bool act = j < CC;
  int jj = act ? j : 0;
  int len = seq_len[b];
  const float* pb = probs + (size_t)b * TT * PR;
  const int* tg = target + b * TT;

  // gold score, lanes parallel over t
  float gsum = 0.f;
  for (int t = j; t < len; t += 64) {
    int cur = tg[t];
    gsum += __logf(pb[(size_t)t * PR + cur]);
    if (t >= 1) gsum += trans[tg[t - 1] * CC + cur];
  }
  gsum = wave_reduce_sum64(gsum);

  // alpha chain: lane j owns a_j (probability domain, renormalized per segment)
  float a = act ? pb[jj] * __expf(startv[jj]) : 0.f;
  float Z = 0.f;
  int gbase = b * SS;

  for (int s = 0; s < SS; ++s) {
    int g = gbase + s;
    float scl = act ? scaleBuf[(size_t)g * CC + jj] : -1e30f;
    float L = act ? (__logf(a) + scl) : -INFINITY;
    float m = wave_reduce_max64(L);
    float at = act ? __expf(L - m) : 0.f;

    const float* Mb = Pbuf + (size_t)g * CC * CC + jj;  // column i at Mb[i*CC]
    float a0 = 0.f, a1 = 0.f, a2 = 0.f, a3 = 0.f;
    #pragma unroll
    for (int i = 0; i < CC; i += 4) {
      a0 += __shfl(at, i + 0, 64) * Mb[(i + 0) * CC];
      a1 += __shfl(at, i + 1, 64) * Mb[(i + 1) * CC];
      a2 += __shfl(at, i + 2, 64) * Mb[(i + 2) * CC];
      a3 += __shfl(at, i + 3, 64) * Mb[(i + 3) * CC];
    }
    float out = (a0 + a1) + (a2 + a3);
    float mass = wave_reduce_sum64(act ? out : 0.f);
    Z += m + __logf(mass);
    a = act ? out / mass : 0.f;
  }

  float ve = act ? a * __expf(endv[jj]) : 0.f;
  float ssum = wave_reduce_sum64(ve);
  float norm = Z + __logf(ssum);

  if (j == 0)
    nll[b] = norm - gsum - startv[tg[0]] - endv[tg[len - 1]];
}

// ---- Kernel C: mean over B ----
__global__ __launch_bounds__(64) void mean_kernel(
    const float* __restrict__ nll, float* __restrict__ out)
{
  float v = nll[threadIdx.x];
  v = wave_reduce_sum64(v);
  if (threadIdx.x == 0) out[0] = v * (1.0f / BB);
}

extern "C" void kernel_launch(void* const* d_in, const int* in_sizes, int n_in,
                              void* d_out, int out_size, void* d_ws, size_t ws_size,
                              hipStream_t stream) {
  const int*   words   = (const int*)d_in[0];
  const int*   seq_len = (const int*)d_in[1];
  const int*   target  = (const int*)d_in[2];
  const float* emb     = (const float*)d_in[3];
  const float* ln_g    = (const float*)d_in[4];
  const float* ln_b    = (const float*)d_in[5];
  const float* W       = (const float*)d_in[6];
  const float* bias    = (const float*)d_in[7];
  const float* trans   = (const float*)d_in[8];
  const float* startv  = (const float*)d_in[9];
  const float* endv    = (const float*)d_in[10];

  float* probs    = (float*)d_ws;                          // 655,360 floats
  float* Pbuf     = probs + (size_t)BB * TT * PR;          // 819,200
  float* scaleBuf = Pbuf + (size_t)NCH * CC;               // 40,960
  float* nll      = scaleBuf + NCH;                        // 64
  float* expE     = nll + BB;                              // 400
  float* out      = (float*)d_out;

  init_expE_kernel<<<1, 512, 0, stream>>>(trans, expE);
  token_probs_kernel<<<512, 256, 0, stream>>>(words, emb, ln_g, ln_b, W, bias,
                                              probs);
  segment_kernel<<<(NCH + 2) / 3, 64, 0, stream>>>(probs, seq_len, expE, Pbuf,
                                                   scaleBuf);
  combine_kernel<<<BB, 64, 0, stream>>>(probs, Pbuf, scaleBuf, seq_len, target,
                                        trans, startv, endv, nll);
  mean_kernel<<<1, 64, 0, stream>>>(nll, out);
}

// Round 7
// 255.294 us; speedup vs baseline: 1.6899x; 1.0320x over previous
//
#include <hip/hip_runtime.h>
#include <math.h>

#define BB 64
#define TT 512
#define DD 256
#define CC 20
#define SS 8             // segments per batch element
#define LL 64            // steps per segment
#define PR 20            // prob row stride (floats)
#define NSEG (BB * SS)   // 512 segments
#define NCH (NSEG * CC)  // 10240 column chains
#define LN_EPS 1e-5f

__device__ __forceinline__ float dpp_sum16(float v) {
  v += __int_as_float(__builtin_amdgcn_update_dpp(0, __float_as_int(v), 0xB1, 0xF, 0xF, true));
  v += __int_as_float(__builtin_amdgcn_update_dpp(0, __float_as_int(v), 0x4E, 0xF, 0xF, true));
  v += __int_as_float(__builtin_amdgcn_update_dpp(0, __float_as_int(v), 0x141, 0xF, 0xF, true));
  v += __int_as_float(__builtin_amdgcn_update_dpp(0, __float_as_int(v), 0x140, 0xF, 0xF, true));
  return v;
}
__device__ __forceinline__ float dpp_max16(float v) {
  v = fmaxf(v, __int_as_float(__builtin_amdgcn_update_dpp(0, __float_as_int(v), 0xB1, 0xF, 0xF, true)));
  v = fmaxf(v, __int_as_float(__builtin_amdgcn_update_dpp(0, __float_as_int(v), 0x4E, 0xF, 0xF, true)));
  v = fmaxf(v, __int_as_float(__builtin_amdgcn_update_dpp(0, __float_as_int(v), 0x141, 0xF, 0xF, true)));
  v = fmaxf(v, __int_as_float(__builtin_amdgcn_update_dpp(0, __float_as_int(v), 0x140, 0xF, 0xF, true)));
  return v;
}
__device__ __forceinline__ float wave_reduce_sum64(float v) {
  #pragma unroll
  for (int off = 32; off > 0; off >>= 1) v += __shfl_xor(v, off, 64);
  return v;
}
__device__ __forceinline__ float wave_reduce_max64(float v) {
  #pragma unroll
  for (int off = 32; off > 0; off >>= 1) v = fmaxf(v, __shfl_xor(v, off, 64));
  return v;
}

// ---- Kernel 0: precompute exp(trans) ----
__global__ __launch_bounds__(512) void init_expE_kernel(
    const float* __restrict__ trans, float* __restrict__ expE)
{
  int i = threadIdx.x;
  if (i < CC * CC) expE[i] = __expf(trans[i]);
}

// ---- Kernel A: emb gather + LN + linear + softmax probs. ----
// 16 lanes/token, 64 tokens per 256-thread block, grid 512.
__global__ __launch_bounds__(256, 1) void token_probs_kernel(
    const int* __restrict__ words, const float* __restrict__ emb,
    const float* __restrict__ ln_g, const float* __restrict__ ln_b,
    const float* __restrict__ W, const float* __restrict__ bias,
    float* __restrict__ probs)
{
  __shared__ __align__(16) float4 sW4[64 * 21];  // [d4][c], stride 21
  __shared__ float sb[CC];
  int tid = threadIdx.x;
  for (int ei = tid; ei < 64 * CC; ei += 256) {
    int d4 = ei / CC, c = ei - d4 * CC;
    int base = 4 * d4 * CC + c;  // W is (D, C) row-major
    sW4[d4 * 21 + c] = make_float4(W[base], W[base + CC], W[base + 2 * CC], W[base + 3 * CC]);
  }
  if (tid < CC) sb[tid] = bias[tid];
  __syncthreads();

  int lane = tid & 63, wave = tid >> 6;
  int sub = lane >> 4, l = lane & 15;

  float4 g0 = ((const float4*)ln_g)[l];
  float4 g1 = ((const float4*)ln_g)[l + 16];
  float4 g2 = ((const float4*)ln_g)[l + 32];
  float4 g3 = ((const float4*)ln_g)[l + 48];
  float4 e0v = ((const float4*)ln_b)[l];
  float4 e1v = ((const float4*)ln_b)[l + 16];
  float4 e2v = ((const float4*)ln_b)[l + 32];
  float4 e3v = ((const float4*)ln_b)[l + 48];

  for (int gidx = 0; gidx < 4; ++gidx) {
    int token = blockIdx.x * 64 + wave * 16 + gidx * 4 + sub;
    int word = words[token];
    const float4* row = (const float4*)(emb + (size_t)word * DD);
    float4 x0 = row[l], x1 = row[l + 16], x2 = row[l + 32], x3 = row[l + 48];

    float s1 = (x0.x + x0.y) + (x0.z + x0.w) + (x1.x + x1.y) + (x1.z + x1.w)
             + (x2.x + x2.y) + (x2.z + x2.w) + (x3.x + x3.y) + (x3.z + x3.w);
    float s2 = x0.x*x0.x + x0.y*x0.y + x0.z*x0.z + x0.w*x0.w
             + x1.x*x1.x + x1.y*x1.y + x1.z*x1.z + x1.w*x1.w
             + x2.x*x2.x + x2.y*x2.y + x2.z*x2.z + x2.w*x2.w
             + x3.x*x3.x + x3.y*x3.y + x3.z*x3.z + x3.w*x3.w;
    s1 = dpp_sum16(s1);
    s2 = dpp_sum16(s2);
    float mu = s1 * (1.f / DD);
    float var = s2 * (1.f / DD) - mu * mu;
    float rr = rsqrtf(var + LN_EPS);

    x0.x = (x0.x - mu) * rr * g0.x + e0v.x;  x0.y = (x0.y - mu) * rr * g0.y + e0v.y;
    x0.z = (x0.z - mu) * rr * g0.z + e0v.z;  x0.w = (x0.w - mu) * rr * g0.w + e0v.w;
    x1.x = (x1.x - mu) * rr * g1.x + e1v.x;  x1.y = (x1.y - mu) * rr * g1.y + e1v.y;
    x1.z = (x1.z - mu) * rr * g1.z + e1v.z;  x1.w = (x1.w - mu) * rr * g1.w + e1v.w;
    x2.x = (x2.x - mu) * rr * g2.x + e2v.x;  x2.y = (x2.y - mu) * rr * g2.y + e2v.y;
    x2.z = (x2.z - mu) * rr * g2.z + e2v.z;  x2.w = (x2.w - mu) * rr * g2.w + e2v.w;
    x3.x = (x3.x - mu) * rr * g3.x + e3v.x;  x3.y = (x3.y - mu) * rr * g3.y + e3v.y;
    x3.z = (x3.z - mu) * rr * g3.z + e3v.z;  x3.w = (x3.w - mu) * rr * g3.w + e3v.w;

    float f0 = 0.f, f1 = 0.f;  // lane l holds feat_l; lanes 0..3 also feat_{16+l}
    #pragma unroll
    for (int c = 0; c < CC; ++c) {
      float4 w0 = sW4[l * 21 + c];
      float4 w1 = sW4[(l + 16) * 21 + c];
      float4 w2 = sW4[(l + 32) * 21 + c];
      float4 w3 = sW4[(l + 48) * 21 + c];
      float pp = (x0.x*w0.x + x0.y*w0.y) + (x0.z*w0.z + x0.w*w0.w)
               + (x1.x*w1.x + x1.y*w1.y) + (x1.z*w1.z + x1.w*w1.w)
               + (x2.x*w2.x + x2.y*w2.y) + (x2.z*w2.z + x2.w*w2.w)
               + (x3.x*w3.x + x3.y*w3.y) + (x3.z*w3.z + x3.w*w3.w);
      pp = dpp_sum16(pp) + sb[c];
      if (c < 16) { if (l == c) f0 = pp; }
      else        { if (l == c - 16) f1 = pp; }
    }

    float m = f0;
    if (l < 4) m = fmaxf(m, f1);
    m = dpp_max16(m);
    float q0 = __expf(f0 - m);
    float q1 = (l < 4) ? __expf(f1 - m) : 0.f;
    float ssum = dpp_sum16(q0 + q1);
    float inv = 1.0f / ssum;

    float* pt = probs + (size_t)token * PR;
    pt[l] = q0 * inv;
    if (l < 4) pt[16 + l] = q1 * inv;
  }
}

// ---- Kernel A2: segment column chains, lane-distributed. ----
// Chain ch = g*20+k evolves column k of segment g: v <- diag(pr_t) E^T v.
// 20 lanes per chain (lane holds ONE scalar state + 20 E scalars), 3 chains
// per 64-thread block. Per-column normalization with log scale.
__global__ __launch_bounds__(64, 1) void segment_kernel(
    const float* __restrict__ probs, const int* __restrict__ seq_len,
    const float* __restrict__ expE,
    float* __restrict__ Pbuf, float* __restrict__ scaleBuf)
{
  int tid = threadIdx.x;
  int grp = tid / 20;           // 0..2 active, 3 idle
  int l = tid - grp * 20;
  int chain = blockIdx.x * 3 + grp;
  bool act = (grp < 3) && (chain < NCH);
  int ch = act ? chain : 0;
  int g = ch / 20, k = ch - g * 20;
  int b = g >> 3, s = g & (SS - 1);
  int len = seq_len[b];
  int base = act ? grp * 20 : 0;

  float E0  = expE[0*CC + l],  E1  = expE[1*CC + l],  E2  = expE[2*CC + l],  E3  = expE[3*CC + l];
  float E4  = expE[4*CC + l],  E5  = expE[5*CC + l],  E6  = expE[6*CC + l],  E7  = expE[7*CC + l];
  float E8  = expE[8*CC + l],  E9  = expE[9*CC + l],  E10 = expE[10*CC + l], E11 = expE[11*CC + l];
  float E12 = expE[12*CC + l], E13 = expE[13*CC + l], E14 = expE[14*CC + l], E15 = expE[15*CC + l];
  float E16 = expE[16*CC + l], E17 = expE[17*CC + l], E18 = expE[18*CC + l], E19 = expE[19*CC + l];

  float v = (l == k) ? 1.f : 0.f;
  const float* pb = probs + (size_t)b * TT * PR + l;
  int t0 = s * LL + 1;
  int tend = min(s * LL + LL, len - 1);

  for (int t = t0; t <= tend; ++t) {
    float pr = pb[t * PR];
    float a0, a1, a2, a3;
    a0  = __shfl(v, base + 0, 64) * E0;
    a1  = __shfl(v, base + 1, 64) * E1;
    a2  = __shfl(v, base + 2, 64) * E2;
    a3  = __shfl(v, base + 3, 64) * E3;
    a0 += __shfl(v, base + 4, 64) * E4;
    a1 += __shfl(v, base + 5, 64) * E5;
    a2 += __shfl(v, base + 6, 64) * E6;
    a3 += __shfl(v, base + 7, 64) * E7;
    a0 += __shfl(v, base + 8, 64) * E8;
    a1 += __shfl(v, base + 9, 64) * E9;
    a2 += __shfl(v, base + 10, 64) * E10;
    a3 += __shfl(v, base + 11, 64) * E11;
    a0 += __shfl(v, base + 12, 64) * E12;
    a1 += __shfl(v, base + 13, 64) * E13;
    a2 += __shfl(v, base + 14, 64) * E14;
    a3 += __shfl(v, base + 15, 64) * E15;
    a0 += __shfl(v, base + 16, 64) * E16;
    a1 += __shfl(v, base + 17, 64) * E17;
    a2 += __shfl(v, base + 18, 64) * E18;
    a3 += __shfl(v, base + 19, 64) * E19;
    v = ((a0 + a1) + (a2 + a3)) * pr;
  }

  __shared__ float sv[64];
  sv[tid] = v;
  __syncthreads();
  float mass = 0.f;
  #pragma unroll
  for (int i = 0; i < CC; ++i) mass += sv[base + i];

  if (act) {
    if (mass > 1e-35f) {
      float inv = 1.0f / mass;
      Pbuf[(size_t)ch * CC + l] = v * inv;
      if (l == 0) scaleBuf[ch] = __logf(mass);
    } else {
      Pbuf[(size_t)ch * CC + l] = 0.f;
      if (l == 0) scaleBuf[ch] = -1e30f;
    }
  }
}

// ---- Kernel B: gold score + serial SS-segment combine from LDS + mean. ----
// All 8 segment matrices (12.8 KB) prefetched coalesced into LDS up-front;
// the serial folds then never touch global memory.
__global__ __launch_bounds__(64, 1) void combine_kernel(
    const float* __restrict__ probs, const float* __restrict__ Pbuf,
    const float* __restrict__ scaleBuf, const int* __restrict__ seq_len,
    const int* __restrict__ target, const float* __restrict__ trans,
    const float* __restrict__ startv, const float* __restrict__ endv,
    float* __restrict__ out)
{
  __shared__ __align__(16) float sM[SS * CC * CC];   // 12.8 KB
  __shared__ float sScale[SS * CC];
  int b = blockIdx.x;
  int j = threadIdx.x;

  // coalesced prefetch: this b's 8 segment matrices are contiguous in Pbuf
  const float4* src = (const float4*)(Pbuf + (size_t)b * SS * CC * CC);
  #pragma unroll
  for (int i = 0; i < SS * CC * CC / 4 / 64; ++i)
    ((float4*)sM)[j + 64 * i] = src[j + 64 * i];
  { int i = SS * CC * CC / 4 / 64 * 64 + j;          // remainder (800 = 12*64+32)
    if (i < SS * CC * CC / 4) ((float4*)sM)[i] = src[i]; }
  for (int i = j; i < SS * CC; i += 64) sScale[i] = scaleBuf[b * SS * CC + i];

  bool act = j < CC;
  int jj = act ? j : 0;
  int len = seq_len[b];
  const float* pb = probs + (size_t)b * TT * PR;
  const int* tg = target + b * TT;

  // gold score, lanes parallel over t
  float gsum = 0.f;
  for (int t = j; t < len; t += 64) {
    int cur = tg[t];
    gsum += __logf(pb[(size_t)t * PR + cur]);
    if (t >= 1) gsum += trans[tg[t - 1] * CC + cur];
  }
  gsum = wave_reduce_sum64(gsum);

  __syncthreads();

  // alpha chain: lane j owns a_j (probability domain, renormalized per segment)
  float a = act ? pb[jj] * __expf(startv[jj]) : 0.f;
  float Z = 0.f;

  for (int s = 0; s < SS; ++s) {
    float scl = act ? sScale[s * CC + jj] : -1e30f;
    float L = act ? (__logf(a) + scl) : -INFINITY;
    float m = wave_reduce_max64(L);
    float at = act ? __expf(L - m) : 0.f;

    const float* Mb = sM + s * CC * CC + jj;   // column i at Mb[i*CC]
    float a0 = 0.f, a1 = 0.f, a2 = 0.f, a3 = 0.f;
    #pragma unroll
    for (int i = 0; i < CC; i += 4) {
      a0 += __shfl(at, i + 0, 64) * Mb[(i + 0) * CC];
      a1 += __shfl(at, i + 1, 64) * Mb[(i + 1) * CC];
      a2 += __shfl(at, i + 2, 64) * Mb[(i + 2) * CC];
      a3 += __shfl(at, i + 3, 64) * Mb[(i + 3) * CC];
    }
    float o = (a0 + a1) + (a2 + a3);
    float mass = wave_reduce_sum64(act ? o : 0.f);
    Z += m + __logf(mass);
    a = act ? o / mass : 0.f;
  }

  float ve = act ? a * __expf(endv[jj]) : 0.f;
  float ssum = wave_reduce_sum64(ve);
  float norm = Z + __logf(ssum);

  if (j == 0) {
    float nll = norm - gsum - startv[tg[0]] - endv[tg[len - 1]];
    atomicAdd(out, nll * (1.0f / BB));
  }
}

extern "C" void kernel_launch(void* const* d_in, const int* in_sizes, int n_in,
                              void* d_out, int out_size, void* d_ws, size_t ws_size,
                              hipStream_t stream) {
  const int*   words   = (const int*)d_in[0];
  const int*   seq_len = (const int*)d_in[1];
  const int*   target  = (const int*)d_in[2];
  const float* emb     = (const float*)d_in[3];
  const float* ln_g    = (const float*)d_in[4];
  const float* ln_b    = (const float*)d_in[5];
  const float* W       = (const float*)d_in[6];
  const float* bias    = (const float*)d_in[7];
  const float* trans   = (const float*)d_in[8];
  const float* startv  = (const float*)d_in[9];
  const float* endv    = (const float*)d_in[10];

  float* probs    = (float*)d_ws;                          // 655,360 floats
  float* Pbuf     = probs + (size_t)BB * TT * PR;          // 204,800
  float* scaleBuf = Pbuf + (size_t)NCH * CC;               // 10,240
  float* expE     = scaleBuf + NCH;                        // 400
  float* out      = (float*)d_out;

  hipMemsetAsync(out, 0, sizeof(float), stream);
  init_expE_kernel<<<1, 512, 0, stream>>>(trans, expE);
  token_probs_kernel<<<512, 256, 0, stream>>>(words, emb, ln_g, ln_b, W, bias,
                                              probs);
  segment_kernel<<<(NCH + 2) / 3, 64, 0, stream>>>(probs, seq_len, expE, Pbuf,
                                                   scaleBuf);
  combine_kernel<<<BB, 64, 0, stream>>>(probs, Pbuf, scaleBuf, seq_len, target,
                                        trans, startv, endv, out);
}

// Round 8
// 197.918 us; speedup vs baseline: 2.1799x; 1.2899x over previous
//
#include <hip/hip_runtime.h>
#include <math.h>

#define BB 64
#define TT 512
#define DD 256
#define CC 20
#define SS 32            // segments per batch element
#define LL 16            // production steps per segment
#define WW 16            // warm-up steps (Birkhoff contraction ~0.34^16 ~ 3e-8)
#define PR 20            // prob row stride (floats)
#define NSEG (BB * SS)   // 2048 vector chains
#define LN_EPS 1e-5f

__device__ __forceinline__ float dpp_sum16(float v) {
  v += __int_as_float(__builtin_amdgcn_update_dpp(0, __float_as_int(v), 0xB1, 0xF, 0xF, true));
  v += __int_as_float(__builtin_amdgcn_update_dpp(0, __float_as_int(v), 0x4E, 0xF, 0xF, true));
  v += __int_as_float(__builtin_amdgcn_update_dpp(0, __float_as_int(v), 0x141, 0xF, 0xF, true));
  v += __int_as_float(__builtin_amdgcn_update_dpp(0, __float_as_int(v), 0x140, 0xF, 0xF, true));
  return v;
}
__device__ __forceinline__ float dpp_max16(float v) {
  v = fmaxf(v, __int_as_float(__builtin_amdgcn_update_dpp(0, __float_as_int(v), 0xB1, 0xF, 0xF, true)));
  v = fmaxf(v, __int_as_float(__builtin_amdgcn_update_dpp(0, __float_as_int(v), 0x4E, 0xF, 0xF, true)));
  v = fmaxf(v, __int_as_float(__builtin_amdgcn_update_dpp(0, __float_as_int(v), 0x141, 0xF, 0xF, true)));
  v = fmaxf(v, __int_as_float(__builtin_amdgcn_update_dpp(0, __float_as_int(v), 0x140, 0xF, 0xF, true)));
  return v;
}
__device__ __forceinline__ float wave_reduce_sum64(float v) {
  #pragma unroll
  for (int off = 32; off > 0; off >>= 1) v += __shfl_xor(v, off, 64);
  return v;
}
__device__ __forceinline__ float wave_reduce_max64(float v) {
  #pragma unroll
  for (int off = 32; off > 0; off >>= 1) v = fmaxf(v, __shfl_xor(v, off, 64));
  return v;
}

// ---- Kernel A: emb gather + LN + linear + softmax probs. ----
// 16 lanes/token, 64 tokens per 256-thread block, grid 512.
__global__ __launch_bounds__(256, 1) void token_probs_kernel(
    const int* __restrict__ words, const float* __restrict__ emb,
    const float* __restrict__ ln_g, const float* __restrict__ ln_b,
    const float* __restrict__ W, const float* __restrict__ bias,
    float* __restrict__ probs)
{
  __shared__ __align__(16) float4 sW4[64 * 21];  // [d4][c], stride 21
  __shared__ float sb[CC];
  int tid = threadIdx.x;
  for (int ei = tid; ei < 64 * CC; ei += 256) {
    int d4 = ei / CC, c = ei - d4 * CC;
    int base = 4 * d4 * CC + c;  // W is (D, C) row-major
    sW4[d4 * 21 + c] = make_float4(W[base], W[base + CC], W[base + 2 * CC], W[base + 3 * CC]);
  }
  if (tid < CC) sb[tid] = bias[tid];
  __syncthreads();

  int lane = tid & 63, wave = tid >> 6;
  int sub = lane >> 4, l = lane & 15;

  float4 g0 = ((const float4*)ln_g)[l];
  float4 g1 = ((const float4*)ln_g)[l + 16];
  float4 g2 = ((const float4*)ln_g)[l + 32];
  float4 g3 = ((const float4*)ln_g)[l + 48];
  float4 e0v = ((const float4*)ln_b)[l];
  float4 e1v = ((const float4*)ln_b)[l + 16];
  float4 e2v = ((const float4*)ln_b)[l + 32];
  float4 e3v = ((const float4*)ln_b)[l + 48];

  for (int gidx = 0; gidx < 4; ++gidx) {
    int token = blockIdx.x * 64 + wave * 16 + gidx * 4 + sub;
    int word = words[token];
    const float4* row = (const float4*)(emb + (size_t)word * DD);
    float4 x0 = row[l], x1 = row[l + 16], x2 = row[l + 32], x3 = row[l + 48];

    float s1 = (x0.x + x0.y) + (x0.z + x0.w) + (x1.x + x1.y) + (x1.z + x1.w)
             + (x2.x + x2.y) + (x2.z + x2.w) + (x3.x + x3.y) + (x3.z + x3.w);
    float s2 = x0.x*x0.x + x0.y*x0.y + x0.z*x0.z + x0.w*x0.w
             + x1.x*x1.x + x1.y*x1.y + x1.z*x1.z + x1.w*x1.w
             + x2.x*x2.x + x2.y*x2.y + x2.z*x2.z + x2.w*x2.w
             + x3.x*x3.x + x3.y*x3.y + x3.z*x3.z + x3.w*x3.w;
    s1 = dpp_sum16(s1);
    s2 = dpp_sum16(s2);
    float mu = s1 * (1.f / DD);
    float var = s2 * (1.f / DD) - mu * mu;
    float rr = rsqrtf(var + LN_EPS);

    x0.x = (x0.x - mu) * rr * g0.x + e0v.x;  x0.y = (x0.y - mu) * rr * g0.y + e0v.y;
    x0.z = (x0.z - mu) * rr * g0.z + e0v.z;  x0.w = (x0.w - mu) * rr * g0.w + e0v.w;
    x1.x = (x1.x - mu) * rr * g1.x + e1v.x;  x1.y = (x1.y - mu) * rr * g1.y + e1v.y;
    x1.z = (x1.z - mu) * rr * g1.z + e1v.z;  x1.w = (x1.w - mu) * rr * g1.w + e1v.w;
    x2.x = (x2.x - mu) * rr * g2.x + e2v.x;  x2.y = (x2.y - mu) * rr * g2.y + e2v.y;
    x2.z = (x2.z - mu) * rr * g2.z + e2v.z;  x2.w = (x2.w - mu) * rr * g2.w + e2v.w;
    x3.x = (x3.x - mu) * rr * g3.x + e3v.x;  x3.y = (x3.y - mu) * rr * g3.y + e3v.y;
    x3.z = (x3.z - mu) * rr * g3.z + e3v.z;  x3.w = (x3.w - mu) * rr * g3.w + e3v.w;

    float f0 = 0.f, f1 = 0.f;  // lane l holds feat_l; lanes 0..3 also feat_{16+l}
    #pragma unroll
    for (int c = 0; c < CC; ++c) {
      float4 w0 = sW4[l * 21 + c];
      float4 w1 = sW4[(l + 16) * 21 + c];
      float4 w2 = sW4[(l + 32) * 21 + c];
      float4 w3 = sW4[(l + 48) * 21 + c];
      float pp = (x0.x*w0.x + x0.y*w0.y) + (x0.z*w0.z + x0.w*w0.w)
               + (x1.x*w1.x + x1.y*w1.y) + (x1.z*w1.z + x1.w*w1.w)
               + (x2.x*w2.x + x2.y*w2.y) + (x2.z*w2.z + x2.w*w2.w)
               + (x3.x*w3.x + x3.y*w3.y) + (x3.z*w3.z + x3.w*w3.w);
      pp = dpp_sum16(pp) + sb[c];
      if (c < 16) { if (l == c) f0 = pp; }
      else        { if (l == c - 16) f1 = pp; }
    }

    float m = f0;
    if (l < 4) m = fmaxf(m, f1);
    m = dpp_max16(m);
    float q0 = __expf(f0 - m);
    float q1 = (l < 4) ? __expf(f1 - m) : 0.f;
    float ssum = dpp_sum16(q0 + q1);
    float inv = 1.0f / ssum;

    float* pt = probs + (size_t)token * PR;
    pt[l] = q0 * inv;
    if (l < 4) pt[16 + l] = q1 * inv;
  }
}

// ---- Kernel A2: warm-restart VECTOR chains (no matrices). ----
// Chain (b,s): evolve v <- diag(pr_t) E^T v. s>0 starts from uniform with WW
// warm-up steps (Birkhoff contraction makes direction f32-exact); records
// partialZ = log(mass_end/mass_mid) over its production range. The segment
// containing t=len-1 also writes the normalized final vector.
// 3 chains of 20 lanes per single-wave block.
__global__ __launch_bounds__(64, 1) void segment_kernel(
    const float* __restrict__ probs, const int* __restrict__ seq_len,
    const float* __restrict__ trans, const float* __restrict__ startv,
    float* __restrict__ partialZ, float* __restrict__ finalA)
{
  int tid = threadIdx.x;
  int grp = tid / 20;           // 0..2 active, 3 idle
  int l = tid - grp * 20;
  int chain = blockIdx.x * 3 + grp;
  bool act = (grp < 3) && (chain < NSEG);
  int ch = act ? chain : 0;
  int b = ch >> 5;              // SS = 32
  int s = ch & (SS - 1);
  int len = seq_len[b];
  int base = act ? grp * 20 : 0;

  // E column l in registers: E_i = exp(trans[i][l])
  float E0  = __expf(trans[0*CC + l]),  E1  = __expf(trans[1*CC + l]);
  float E2  = __expf(trans[2*CC + l]),  E3  = __expf(trans[3*CC + l]);
  float E4  = __expf(trans[4*CC + l]),  E5  = __expf(trans[5*CC + l]);
  float E6  = __expf(trans[6*CC + l]),  E7  = __expf(trans[7*CC + l]);
  float E8  = __expf(trans[8*CC + l]),  E9  = __expf(trans[9*CC + l]);
  float E10 = __expf(trans[10*CC + l]), E11 = __expf(trans[11*CC + l]);
  float E12 = __expf(trans[12*CC + l]), E13 = __expf(trans[13*CC + l]);
  float E14 = __expf(trans[14*CC + l]), E15 = __expf(trans[15*CC + l]);
  float E16 = __expf(trans[16*CC + l]), E17 = __expf(trans[17*CC + l]);
  float E18 = __expf(trans[18*CC + l]), E19 = __expf(trans[19*CC + l]);

  int prod_start = s * LL + 1;
  int prod_end   = min(s * LL + LL, len - 1);
  bool empty = prod_start > prod_end;

  const float* pb = probs + (size_t)b * TT * PR + l;

  float v = (s == 0) ? pb[0] * __expf(startv[l]) : 1.0f;

#define STEP(t) do {                                            \
    float pr = pb[(t) * PR];                                    \
    float a0, a1, a2, a3;                                       \
    a0  = __shfl(v, base + 0, 64) * E0;                         \
    a1  = __shfl(v, base + 1, 64) * E1;                         \
    a2  = __shfl(v, base + 2, 64) * E2;                         \
    a3  = __shfl(v, base + 3, 64) * E3;                         \
    a0 += __shfl(v, base + 4, 64) * E4;                         \
    a1 += __shfl(v, base + 5, 64) * E5;                         \
    a2 += __shfl(v, base + 6, 64) * E6;                         \
    a3 += __shfl(v, base + 7, 64) * E7;                         \
    a0 += __shfl(v, base + 8, 64) * E8;                         \
    a1 += __shfl(v, base + 9, 64) * E9;                         \
    a2 += __shfl(v, base + 10, 64) * E10;                       \
    a3 += __shfl(v, base + 11, 64) * E11;                       \
    a0 += __shfl(v, base + 12, 64) * E12;                       \
    a1 += __shfl(v, base + 13, 64) * E13;                       \
    a2 += __shfl(v, base + 14, 64) * E14;                       \
    a3 += __shfl(v, base + 15, 64) * E15;                       \
    a0 += __shfl(v, base + 16, 64) * E16;                       \
    a1 += __shfl(v, base + 17, 64) * E17;                       \
    a2 += __shfl(v, base + 18, 64) * E18;                       \
    a3 += __shfl(v, base + 19, 64) * E19;                       \
    v = ((a0 + a1) + (a2 + a3)) * pr;                           \
  } while (0)

  // warm-up (s>0 only): [prod_start-WW, prod_start-1]; all < len-1 when non-empty
  int nwarm = (s == 0 || empty) ? 0 : WW;
  for (int t = prod_start - nwarm; t < prod_start; ++t) STEP(t);

  __shared__ float sv[64];
  sv[tid] = v;
  __syncthreads();
  float Smid = 0.f;
  #pragma unroll
  for (int i = 0; i < CC; ++i) Smid += sv[base + i];
  __syncthreads();

  if (!empty) {
    for (int t = prod_start; t <= prod_end; ++t) STEP(t);
  }
#undef STEP

  sv[tid] = v;
  __syncthreads();
  float Send = 0.f;
  #pragma unroll
  for (int i = 0; i < CC; ++i) Send += sv[base + i];

  if (act) {
    float pz;
    if (empty)       pz = 0.f;
    else if (s == 0) pz = __logf(Send);               // includes initial mass
    else             pz = __logf(Send) - __logf(Smid);
    if (l == 0) partialZ[ch] = pz;
    if (!empty && s == (len - 2) / LL)
      finalA[b * CC + l] = v / Send;                  // normalized alpha at len-1
  }
}

// ---- Kernel B: gold score + sum partials + final lse + mean. ----
__global__ __launch_bounds__(64, 1) void combine_kernel(
    const float* __restrict__ probs, const float* __restrict__ partialZ,
    const float* __restrict__ finalA, const int* __restrict__ seq_len,
    const int* __restrict__ target, const float* __restrict__ trans,
    const float* __restrict__ startv, const float* __restrict__ endv,
    float* __restrict__ out)
{
  int b = blockIdx.x;
  int j = threadIdx.x;
  int len = seq_len[b];
  const float* pb = probs + (size_t)b * TT * PR;
  const int* tg = target + b * TT;

  // gold score, lanes parallel over t
  float gsum = 0.f;
  for (int t = j; t < len; t += 64) {
    int cur = tg[t];
    gsum += __logf(pb[(size_t)t * PR + cur]);
    if (t >= 1) gsum += trans[tg[t - 1] * CC + cur];
  }
  gsum = wave_reduce_sum64(gsum);

  float Z;
  if (len == 1) {
    float val = (j < CC) ? __logf(pb[j]) + startv[j] + endv[j] : -INFINITY;
    float m = wave_reduce_max64(val);
    float ssum = wave_reduce_sum64((j < CC) ? __expf(val - m) : 0.f);
    Z = m + __logf(ssum);
  } else {
    float pz = (j < SS) ? partialZ[b * SS + j] : 0.f;
    pz = wave_reduce_sum64(pz);
    float ve = (j < CC) ? finalA[b * CC + j] * __expf(endv[j]) : 0.f;
    float ssum = wave_reduce_sum64(ve);
    Z = pz + __logf(ssum);
  }

  if (j == 0) {
    float nll = Z - gsum - startv[tg[0]] - endv[tg[len - 1]];
    atomicAdd(out, nll * (1.0f / BB));
  }
}

extern "C" void kernel_launch(void* const* d_in, const int* in_sizes, int n_in,
                              void* d_out, int out_size, void* d_ws, size_t ws_size,
                              hipStream_t stream) {
  const int*   words   = (const int*)d_in[0];
  const int*   seq_len = (const int*)d_in[1];
  const int*   target  = (const int*)d_in[2];
  const float* emb     = (const float*)d_in[3];
  const float* ln_g    = (const float*)d_in[4];
  const float* ln_b    = (const float*)d_in[5];
  const float* W       = (const float*)d_in[6];
  const float* bias    = (const float*)d_in[7];
  const float* trans   = (const float*)d_in[8];
  const float* startv  = (const float*)d_in[9];
  const float* endv    = (const float*)d_in[10];

  float* probs    = (float*)d_ws;                          // 655,360 floats
  float* partialZ = probs + (size_t)BB * TT * PR;          // 2,048
  float* finalA   = partialZ + NSEG;                       // 1,280
  float* out      = (float*)d_out;

  hipMemsetAsync(out, 0, sizeof(float), stream);
  token_probs_kernel<<<512, 256, 0, stream>>>(words, emb, ln_g, ln_b, W, bias,
                                              probs);
  segment_kernel<<<(NSEG + 2) / 3, 64, 0, stream>>>(probs, seq_len, trans,
                                                    startv, partialZ, finalA);
  combine_kernel<<<BB, 64, 0, stream>>>(probs, partialZ, finalA, seq_len,
                                        target, trans, startv, endv, out);
}

// Round 9
// 184.752 us; speedup vs baseline: 2.3352x; 1.0713x over previous
//
#include <hip/hip_runtime.h>
#include <math.h>

#define BB 64
#define TT 512
#define DD 256
#define CC 20
#define SS 32            // segments per batch element
#define LL 16            // production steps per segment
#define WW 16            // warm-up steps (Birkhoff contraction ~0.34^16 ~ 3e-8)
#define PR 20            // prob row stride (floats)
#define NSEG (BB * SS)   // 2048 vector chains
#define LN_EPS 1e-5f

__device__ __forceinline__ float dpp_sum16(float v) {
  v += __int_as_float(__builtin_amdgcn_update_dpp(0, __float_as_int(v), 0xB1, 0xF, 0xF, true));
  v += __int_as_float(__builtin_amdgcn_update_dpp(0, __float_as_int(v), 0x4E, 0xF, 0xF, true));
  v += __int_as_float(__builtin_amdgcn_update_dpp(0, __float_as_int(v), 0x141, 0xF, 0xF, true));
  v += __int_as_float(__builtin_amdgcn_update_dpp(0, __float_as_int(v), 0x140, 0xF, 0xF, true));
  return v;
}
__device__ __forceinline__ float dpp_max16(float v) {
  v = fmaxf(v, __int_as_float(__builtin_amdgcn_update_dpp(0, __float_as_int(v), 0xB1, 0xF, 0xF, true)));
  v = fmaxf(v, __int_as_float(__builtin_amdgcn_update_dpp(0, __float_as_int(v), 0x4E, 0xF, 0xF, true)));
  v = fmaxf(v, __int_as_float(__builtin_amdgcn_update_dpp(0, __float_as_int(v), 0x141, 0xF, 0xF, true)));
  v = fmaxf(v, __int_as_float(__builtin_amdgcn_update_dpp(0, __float_as_int(v), 0x140, 0xF, 0xF, true)));
  return v;
}
__device__ __forceinline__ float wave_reduce_sum64(float v) {
  #pragma unroll
  for (int off = 32; off > 0; off >>= 1) v += __shfl_xor(v, off, 64);
  return v;
}
__device__ __forceinline__ float wave_reduce_max64(float v) {
  #pragma unroll
  for (int off = 32; off > 0; off >>= 1) v = fmaxf(v, __shfl_xor(v, off, 64));
  return v;
}

// ---- Kernel A: emb gather + LN + linear + softmax probs. ----
// 16 lanes per token, ONE token per group, 16 tokens per 256-thread block,
// grid 2048 -> 8192 waves (~28 waves/CU) to hide random-gather latency.
__global__ __launch_bounds__(256, 1) void token_probs_kernel(
    const int* __restrict__ words, const float* __restrict__ emb,
    const float* __restrict__ ln_g, const float* __restrict__ ln_b,
    const float* __restrict__ W, const float* __restrict__ bias,
    float* __restrict__ probs)
{
  __shared__ __align__(16) float4 sW4[64 * 21];  // [d4][c], stride 21
  __shared__ float sb[CC];
  int tid = threadIdx.x;
  for (int ei = tid; ei < 64 * CC; ei += 256) {
    int d4 = ei / CC, c = ei - d4 * CC;
    int base = 4 * d4 * CC + c;  // W is (D, C) row-major
    sW4[d4 * 21 + c] = make_float4(W[base], W[base + CC], W[base + 2 * CC], W[base + 3 * CC]);
  }
  if (tid < CC) sb[tid] = bias[tid];
  __syncthreads();

  int l = tid & 15;
  int token = blockIdx.x * 16 + (tid >> 4);

  int word = words[token];
  const float4* row = (const float4*)(emb + (size_t)word * DD);
  float4 x0 = row[l], x1 = row[l + 16], x2 = row[l + 32], x3 = row[l + 48];

  float4 g0 = ((const float4*)ln_g)[l];
  float4 g1 = ((const float4*)ln_g)[l + 16];
  float4 g2 = ((const float4*)ln_g)[l + 32];
  float4 g3 = ((const float4*)ln_g)[l + 48];
  float4 e0v = ((const float4*)ln_b)[l];
  float4 e1v = ((const float4*)ln_b)[l + 16];
  float4 e2v = ((const float4*)ln_b)[l + 32];
  float4 e3v = ((const float4*)ln_b)[l + 48];

  float s1 = (x0.x + x0.y) + (x0.z + x0.w) + (x1.x + x1.y) + (x1.z + x1.w)
           + (x2.x + x2.y) + (x2.z + x2.w) + (x3.x + x3.y) + (x3.z + x3.w);
  float s2 = x0.x*x0.x + x0.y*x0.y + x0.z*x0.z + x0.w*x0.w
           + x1.x*x1.x + x1.y*x1.y + x1.z*x1.z + x1.w*x1.w
           + x2.x*x2.x + x2.y*x2.y + x2.z*x2.z + x2.w*x2.w
           + x3.x*x3.x + x3.y*x3.y + x3.z*x3.z + x3.w*x3.w;
  s1 = dpp_sum16(s1);
  s2 = dpp_sum16(s2);
  float mu = s1 * (1.f / DD);
  float var = s2 * (1.f / DD) - mu * mu;
  float rr = rsqrtf(var + LN_EPS);

  x0.x = (x0.x - mu) * rr * g0.x + e0v.x;  x0.y = (x0.y - mu) * rr * g0.y + e0v.y;
  x0.z = (x0.z - mu) * rr * g0.z + e0v.z;  x0.w = (x0.w - mu) * rr * g0.w + e0v.w;
  x1.x = (x1.x - mu) * rr * g1.x + e1v.x;  x1.y = (x1.y - mu) * rr * g1.y + e1v.y;
  x1.z = (x1.z - mu) * rr * g1.z + e1v.z;  x1.w = (x1.w - mu) * rr * g1.w + e1v.w;
  x2.x = (x2.x - mu) * rr * g2.x + e2v.x;  x2.y = (x2.y - mu) * rr * g2.y + e2v.y;
  x2.z = (x2.z - mu) * rr * g2.z + e2v.z;  x2.w = (x2.w - mu) * rr * g2.w + e2v.w;
  x3.x = (x3.x - mu) * rr * g3.x + e3v.x;  x3.y = (x3.y - mu) * rr * g3.y + e3v.y;
  x3.z = (x3.z - mu) * rr * g3.z + e3v.z;  x3.w = (x3.w - mu) * rr * g3.w + e3v.w;

  float f0 = 0.f, f1 = 0.f;  // lane l holds feat_l; lanes 0..3 also feat_{16+l}
  #pragma unroll
  for (int c = 0; c < CC; ++c) {
    float4 w0 = sW4[l * 21 + c];
    float4 w1 = sW4[(l + 16) * 21 + c];
    float4 w2 = sW4[(l + 32) * 21 + c];
    float4 w3 = sW4[(l + 48) * 21 + c];
    float pp = (x0.x*w0.x + x0.y*w0.y) + (x0.z*w0.z + x0.w*w0.w)
             + (x1.x*w1.x + x1.y*w1.y) + (x1.z*w1.z + x1.w*w1.w)
             + (x2.x*w2.x + x2.y*w2.y) + (x2.z*w2.z + x2.w*w2.w)
             + (x3.x*w3.x + x3.y*w3.y) + (x3.z*w3.z + x3.w*w3.w);
    pp = dpp_sum16(pp) + sb[c];
    if (c < 16) { if (l == c) f0 = pp; }
    else        { if (l == c - 16) f1 = pp; }
  }

  float m = f0;
  if (l < 4) m = fmaxf(m, f1);
  m = dpp_max16(m);
  float q0 = __expf(f0 - m);
  float q1 = (l < 4) ? __expf(f1 - m) : 0.f;
  float ssum = dpp_sum16(q0 + q1);
  float inv = 1.0f / ssum;

  float* pt = probs + (size_t)token * PR;
  pt[l] = q0 * inv;
  if (l < 4) pt[16 + l] = q1 * inv;
}

// ---- Kernel A2: warm-restart VECTOR chains (no matrices). ----
// Chain (b,s): evolve v <- diag(pr_t) E^T v. s>0 starts from uniform with WW
// warm-up steps (Birkhoff contraction makes direction f32-exact); records
// partialZ = log(mass_end/mass_mid) over its production range. The segment
// containing t=len-1 also writes the normalized final vector.
// 3 chains of 20 lanes per single-wave block.
__global__ __launch_bounds__(64, 1) void segment_kernel(
    const float* __restrict__ probs, const int* __restrict__ seq_len,
    const float* __restrict__ trans, const float* __restrict__ startv,
    float* __restrict__ partialZ, float* __restrict__ finalA)
{
  int tid = threadIdx.x;
  int grp = tid / 20;           // 0..2 active, 3 idle
  int l = tid - grp * 20;
  int chain = blockIdx.x * 3 + grp;
  bool act = (grp < 3) && (chain < NSEG);
  int ch = act ? chain : 0;
  int b = ch >> 5;              // SS = 32
  int s = ch & (SS - 1);
  int len = seq_len[b];
  int base = act ? grp * 20 : 0;

  // E column l in registers: E_i = exp(trans[i][l])
  float E0  = __expf(trans[0*CC + l]),  E1  = __expf(trans[1*CC + l]);
  float E2  = __expf(trans[2*CC + l]),  E3  = __expf(trans[3*CC + l]);
  float E4  = __expf(trans[4*CC + l]),  E5  = __expf(trans[5*CC + l]);
  float E6  = __expf(trans[6*CC + l]),  E7  = __expf(trans[7*CC + l]);
  float E8  = __expf(trans[8*CC + l]),  E9  = __expf(trans[9*CC + l]);
  float E10 = __expf(trans[10*CC + l]), E11 = __expf(trans[11*CC + l]);
  float E12 = __expf(trans[12*CC + l]), E13 = __expf(trans[13*CC + l]);
  float E14 = __expf(trans[14*CC + l]), E15 = __expf(trans[15*CC + l]);
  float E16 = __expf(trans[16*CC + l]), E17 = __expf(trans[17*CC + l]);
  float E18 = __expf(trans[18*CC + l]), E19 = __expf(trans[19*CC + l]);

  int prod_start = s * LL + 1;
  int prod_end   = min(s * LL + LL, len - 1);
  bool empty = prod_start > prod_end;

  const float* pb = probs + (size_t)b * TT * PR + l;

  float v = (s == 0) ? pb[0] * __expf(startv[l]) : 1.0f;

#define STEP(t) do {                                            \
    float pr = pb[(t) * PR];                                    \
    float a0, a1, a2, a3;                                       \
    a0  = __shfl(v, base + 0, 64) * E0;                         \
    a1  = __shfl(v, base + 1, 64) * E1;                         \
    a2  = __shfl(v, base + 2, 64) * E2;                         \
    a3  = __shfl(v, base + 3, 64) * E3;                         \
    a0 += __shfl(v, base + 4, 64) * E4;                         \
    a1 += __shfl(v, base + 5, 64) * E5;                         \
    a2 += __shfl(v, base + 6, 64) * E6;                         \
    a3 += __shfl(v, base + 7, 64) * E7;                         \
    a0 += __shfl(v, base + 8, 64) * E8;                         \
    a1 += __shfl(v, base + 9, 64) * E9;                         \
    a2 += __shfl(v, base + 10, 64) * E10;                       \
    a3 += __shfl(v, base + 11, 64) * E11;                       \
    a0 += __shfl(v, base + 12, 64) * E12;                       \
    a1 += __shfl(v, base + 13, 64) * E13;                       \
    a2 += __shfl(v, base + 14, 64) * E14;                       \
    a3 += __shfl(v, base + 15, 64) * E15;                       \
    a0 += __shfl(v, base + 16, 64) * E16;                       \
    a1 += __shfl(v, base + 17, 64) * E17;                       \
    a2 += __shfl(v, base + 18, 64) * E18;                       \
    a3 += __shfl(v, base + 19, 64) * E19;                       \
    v = ((a0 + a1) + (a2 + a3)) * pr;                           \
  } while (0)

  // warm-up (s>0 only): [prod_start-WW, prod_start-1]; all < len-1 when non-empty
  int nwarm = (s == 0 || empty) ? 0 : WW;
  for (int t = prod_start - nwarm; t < prod_start; ++t) STEP(t);

  __shared__ float sv[64];
  sv[tid] = v;
  __syncthreads();
  float Smid = 0.f;
  #pragma unroll
  for (int i = 0; i < CC; ++i) Smid += sv[base + i];
  __syncthreads();

  if (!empty) {
    for (int t = prod_start; t <= prod_end; ++t) STEP(t);
  }
#undef STEP

  sv[tid] = v;
  __syncthreads();
  float Send = 0.f;
  #pragma unroll
  for (int i = 0; i < CC; ++i) Send += sv[base + i];

  if (act) {
    float pz;
    if (empty)       pz = 0.f;
    else if (s == 0) pz = __logf(Send);               // includes initial mass
    else             pz = __logf(Send) - __logf(Smid);
    if (l == 0) partialZ[ch] = pz;
    if (!empty && s == (len - 2) / LL)
      finalA[b * CC + l] = v / Send;                  // normalized alpha at len-1
  }
}

// ---- Kernel B: gold score + sum partials + final lse + mean. ----
__global__ __launch_bounds__(64, 1) void combine_kernel(
    const float* __restrict__ probs, const float* __restrict__ partialZ,
    const float* __restrict__ finalA, const int* __restrict__ seq_len,
    const int* __restrict__ target, const float* __restrict__ trans,
    const float* __restrict__ startv, const float* __restrict__ endv,
    float* __restrict__ out)
{
  int b = blockIdx.x;
  int j = threadIdx.x;
  int len = seq_len[b];
  const float* pb = probs + (size_t)b * TT * PR;
  const int* tg = target + b * TT;

  // gold score, lanes parallel over t
  float gsum = 0.f;
  for (int t = j; t < len; t += 64) {
    int cur = tg[t];
    gsum += __logf(pb[(size_t)t * PR + cur]);
    if (t >= 1) gsum += trans[tg[t - 1] * CC + cur];
  }
  gsum = wave_reduce_sum64(gsum);

  float Z;
  if (len == 1) {
    float val = (j < CC) ? __logf(pb[j]) + startv[j] + endv[j] : -INFINITY;
    float m = wave_reduce_max64(val);
    float ssum = wave_reduce_sum64((j < CC) ? __expf(val - m) : 0.f);
    Z = m + __logf(ssum);
  } else {
    float pz = (j < SS) ? partialZ[b * SS + j] : 0.f;
    pz = wave_reduce_sum64(pz);
    float ve = (j < CC) ? finalA[b * CC + j] * __expf(endv[j]) : 0.f;
    float ssum = wave_reduce_sum64(ve);
    Z = pz + __logf(ssum);
  }

  if (j == 0) {
    float nll = Z - gsum - startv[tg[0]] - endv[tg[len - 1]];
    atomicAdd(out, nll * (1.0f / BB));
  }
}

extern "C" void kernel_launch(void* const* d_in, const int* in_sizes, int n_in,
                              void* d_out, int out_size, void* d_ws, size_t ws_size,
                              hipStream_t stream) {
  const int*   words   = (const int*)d_in[0];
  const int*   seq_len = (const int*)d_in[1];
  const int*   target  = (const int*)d_in[2];
  const float* emb     = (const float*)d_in[3];
  const float* ln_g    = (const float*)d_in[4];
  const float* ln_b    = (const float*)d_in[5];
  const float* W       = (const float*)d_in[6];
  const float* bias    = (const float*)d_in[7];
  const float* trans   = (const float*)d_in[8];
  const float* startv  = (const float*)d_in[9];
  const float* endv    = (const float*)d_in[10];

  float* probs    = (float*)d_ws;                          // 655,360 floats
  float* partialZ = probs + (size_t)BB * TT * PR;          // 2,048
  float* finalA   = partialZ + NSEG;                       // 1,280
  float* out      = (float*)d_out;

  hipMemsetAsync(out, 0, sizeof(float), stream);
  token_probs_kernel<<<2048, 256, 0, stream>>>(words, emb, ln_g, ln_b, W, bias,
                                               probs);
  segment_kernel<<<(NSEG + 2) / 3, 64, 0, stream>>>(probs, seq_len, trans,
                                                    startv, partialZ, finalA);
  combine_kernel<<<BB, 64, 0, stream>>>(probs, partialZ, finalA, seq_len,
                                        target, trans, startv, endv, out);
}

// Round 10
// 180.617 us; speedup vs baseline: 2.3887x; 1.0229x over previous
//
#include <hip/hip_runtime.h>
#include <math.h>

#define BB 64
#define TT 512
#define DD 256
#define CC 20
#define SS 32            // segments per batch element
#define LL 16            // production steps per segment
#define WW 16            // warm-up steps (Birkhoff contraction ~0.34^16 ~ 3e-8)
#define PR 20            // prob row stride (floats)
#define NSEG (BB * SS)   // 2048 vector chains
#define LN_EPS 1e-5f

__device__ __forceinline__ float dpp_sum16(float v) {
  v += __int_as_float(__builtin_amdgcn_update_dpp(0, __float_as_int(v), 0xB1, 0xF, 0xF, true));
  v += __int_as_float(__builtin_amdgcn_update_dpp(0, __float_as_int(v), 0x4E, 0xF, 0xF, true));
  v += __int_as_float(__builtin_amdgcn_update_dpp(0, __float_as_int(v), 0x141, 0xF, 0xF, true));
  v += __int_as_float(__builtin_amdgcn_update_dpp(0, __float_as_int(v), 0x140, 0xF, 0xF, true));
  return v;
}
__device__ __forceinline__ float dpp_max16(float v) {
  v = fmaxf(v, __int_as_float(__builtin_amdgcn_update_dpp(0, __float_as_int(v), 0xB1, 0xF, 0xF, true)));
  v = fmaxf(v, __int_as_float(__builtin_amdgcn_update_dpp(0, __float_as_int(v), 0x4E, 0xF, 0xF, true)));
  v = fmaxf(v, __int_as_float(__builtin_amdgcn_update_dpp(0, __float_as_int(v), 0x141, 0xF, 0xF, true)));
  v = fmaxf(v, __int_as_float(__builtin_amdgcn_update_dpp(0, __float_as_int(v), 0x140, 0xF, 0xF, true)));
  return v;
}
__device__ __forceinline__ float wave_reduce_sum64(float v) {
  #pragma unroll
  for (int off = 32; off > 0; off >>= 1) v += __shfl_xor(v, off, 64);
  return v;
}
__device__ __forceinline__ float wave_reduce_max64(float v) {
  #pragma unroll
  for (int off = 32; off > 0; off >>= 1) v = fmaxf(v, __shfl_xor(v, off, 64));
  return v;
}

// ---- Kernel A: emb gather + LN + linear + softmax probs + gold contribution ----
// 16 lanes per token, 16 tokens per 256-thread block, grid 2048.
// Block covers t in [ (blk%32)*16, +16 ) of b = blk/32 -> early exit for
// padding blocks (avg ~half). Also emits the FULL per-token gold contribution
// (emit + trans + start/end) so combine never does scattered loads.
__global__ __launch_bounds__(256, 1) void token_probs_kernel(
    const int* __restrict__ words, const float* __restrict__ emb,
    const float* __restrict__ ln_g, const float* __restrict__ ln_b,
    const float* __restrict__ W, const float* __restrict__ bias,
    const int* __restrict__ seq_len, const int* __restrict__ target,
    const float* __restrict__ trans, const float* __restrict__ startv,
    const float* __restrict__ endv,
    float* __restrict__ probs, float* __restrict__ goldEmit)
{
  int b = blockIdx.x >> 5;
  int t0 = (blockIdx.x & 31) << 4;
  int len = seq_len[b];
  if (t0 >= len) return;                       // whole block is padding

  __shared__ __align__(16) float4 sW4[64 * 21];  // [d4][c], stride 21
  __shared__ float sb[CC];
  int tid = threadIdx.x;
  for (int ei = tid; ei < 64 * CC; ei += 256) {
    int d4 = ei / CC, c = ei - d4 * CC;
    int base = 4 * d4 * CC + c;  // W is (D, C) row-major
    sW4[d4 * 21 + c] = make_float4(W[base], W[base + CC], W[base + 2 * CC], W[base + 3 * CC]);
  }
  if (tid < CC) sb[tid] = bias[tid];
  __syncthreads();

  int l = tid & 15;
  int t = t0 + (tid >> 4);
  if (t >= len) return;                        // padding tail inside block
  int token = (b << 9) + t;

  int word = words[token];
  const float4* row = (const float4*)(emb + (size_t)word * DD);
  float4 x0 = row[l], x1 = row[l + 16], x2 = row[l + 32], x3 = row[l + 48];

  float4 g0 = ((const float4*)ln_g)[l];
  float4 g1 = ((const float4*)ln_g)[l + 16];
  float4 g2 = ((const float4*)ln_g)[l + 32];
  float4 g3 = ((const float4*)ln_g)[l + 48];
  float4 e0v = ((const float4*)ln_b)[l];
  float4 e1v = ((const float4*)ln_b)[l + 16];
  float4 e2v = ((const float4*)ln_b)[l + 32];
  float4 e3v = ((const float4*)ln_b)[l + 48];

  float s1 = (x0.x + x0.y) + (x0.z + x0.w) + (x1.x + x1.y) + (x1.z + x1.w)
           + (x2.x + x2.y) + (x2.z + x2.w) + (x3.x + x3.y) + (x3.z + x3.w);
  float s2 = x0.x*x0.x + x0.y*x0.y + x0.z*x0.z + x0.w*x0.w
           + x1.x*x1.x + x1.y*x1.y + x1.z*x1.z + x1.w*x1.w
           + x2.x*x2.x + x2.y*x2.y + x2.z*x2.z + x2.w*x2.w
           + x3.x*x3.x + x3.y*x3.y + x3.z*x3.z + x3.w*x3.w;
  s1 = dpp_sum16(s1);
  s2 = dpp_sum16(s2);
  float mu = s1 * (1.f / DD);
  float var = s2 * (1.f / DD) - mu * mu;
  float rr = rsqrtf(var + LN_EPS);

  x0.x = (x0.x - mu) * rr * g0.x + e0v.x;  x0.y = (x0.y - mu) * rr * g0.y + e0v.y;
  x0.z = (x0.z - mu) * rr * g0.z + e0v.z;  x0.w = (x0.w - mu) * rr * g0.w + e0v.w;
  x1.x = (x1.x - mu) * rr * g1.x + e1v.x;  x1.y = (x1.y - mu) * rr * g1.y + e1v.y;
  x1.z = (x1.z - mu) * rr * g1.z + e1v.z;  x1.w = (x1.w - mu) * rr * g1.w + e1v.w;
  x2.x = (x2.x - mu) * rr * g2.x + e2v.x;  x2.y = (x2.y - mu) * rr * g2.y + e2v.y;
  x2.z = (x2.z - mu) * rr * g2.z + e2v.z;  x2.w = (x2.w - mu) * rr * g2.w + e2v.w;
  x3.x = (x3.x - mu) * rr * g3.x + e3v.x;  x3.y = (x3.y - mu) * rr * g3.y + e3v.y;
  x3.z = (x3.z - mu) * rr * g3.z + e3v.z;  x3.w = (x3.w - mu) * rr * g3.w + e3v.w;

  int tgt = target[token];
  float f0 = 0.f, f1 = 0.f;  // lane l holds feat_l; lanes 0..3 also feat_{16+l}
  float ftgt = 0.f;          // contribution toward feats[tgt] (one lane nonzero)
  #pragma unroll
  for (int c = 0; c < CC; ++c) {
    float4 w0 = sW4[l * 21 + c];
    float4 w1 = sW4[(l + 16) * 21 + c];
    float4 w2 = sW4[(l + 32) * 21 + c];
    float4 w3 = sW4[(l + 48) * 21 + c];
    float pp = (x0.x*w0.x + x0.y*w0.y) + (x0.z*w0.z + x0.w*w0.w)
             + (x1.x*w1.x + x1.y*w1.y) + (x1.z*w1.z + x1.w*w1.w)
             + (x2.x*w2.x + x2.y*w2.y) + (x2.z*w2.z + x2.w*w2.w)
             + (x3.x*w3.x + x3.y*w3.y) + (x3.z*w3.z + x3.w*w3.w);
    pp = dpp_sum16(pp) + sb[c];
    if (c < 16) { if (l == c) f0 = pp; }
    else        { if (l == c - 16) f1 = pp; }
    if (c < 16) { if (l == c && tgt == c) ftgt = pp; }
    else        { if (l == c - 16 && tgt == c) ftgt = pp; }
  }

  float m = f0;
  if (l < 4) m = fmaxf(m, f1);
  m = dpp_max16(m);
  float q0 = __expf(f0 - m);
  float q1 = (l < 4) ? __expf(f1 - m) : 0.f;
  float ssum = dpp_sum16(q0 + q1);
  float inv = 1.0f / ssum;
  float lsm = m + __logf(ssum);
  ftgt = dpp_sum16(ftgt);      // broadcast feats[tgt] to all 16 lanes

  float* pt = probs + (size_t)token * PR;
  pt[l] = q0 * inv;
  if (l < 4) pt[16 + l] = q1 * inv;

  if (l == 0) {
    float g = ftgt - lsm;
    if (t > 0) g += trans[target[token - 1] * CC + tgt];
    else       g += startv[tgt];
    if (t == len - 1) g += endv[tgt];
    goldEmit[token] = g;
  }
}

// ---- Kernel A2: warm-restart VECTOR chains (no matrices). ----
__global__ __launch_bounds__(64, 1) void segment_kernel(
    const float* __restrict__ probs, const int* __restrict__ seq_len,
    const float* __restrict__ trans, const float* __restrict__ startv,
    float* __restrict__ partialZ, float* __restrict__ finalA)
{
  int tid = threadIdx.x;
  int grp = tid / 20;           // 0..2 active, 3 idle
  int l = tid - grp * 20;
  int chain = blockIdx.x * 3 + grp;
  bool act = (grp < 3) && (chain < NSEG);
  int ch = act ? chain : 0;
  int b = ch >> 5;              // SS = 32
  int s = ch & (SS - 1);
  int len = seq_len[b];
  int base = act ? grp * 20 : 0;

  int prod_start = s * LL + 1;
  int prod_end   = min(s * LL + LL, len - 1);
  bool empty = prod_start > prod_end;

  // fast path: every chain in this block is empty -> write zeros, exit
  if (__ballot(act && !empty) == 0ull) {
    if (act && l == 0) partialZ[ch] = 0.f;
    return;
  }

  // E column l in registers: E_i = exp(trans[i][l])
  float E0  = __expf(trans[0*CC + l]),  E1  = __expf(trans[1*CC + l]);
  float E2  = __expf(trans[2*CC + l]),  E3  = __expf(trans[3*CC + l]);
  float E4  = __expf(trans[4*CC + l]),  E5  = __expf(trans[5*CC + l]);
  float E6  = __expf(trans[6*CC + l]),  E7  = __expf(trans[7*CC + l]);
  float E8  = __expf(trans[8*CC + l]),  E9  = __expf(trans[9*CC + l]);
  float E10 = __expf(trans[10*CC + l]), E11 = __expf(trans[11*CC + l]);
  float E12 = __expf(trans[12*CC + l]), E13 = __expf(trans[13*CC + l]);
  float E14 = __expf(trans[14*CC + l]), E15 = __expf(trans[15*CC + l]);
  float E16 = __expf(trans[16*CC + l]), E17 = __expf(trans[17*CC + l]);
  float E18 = __expf(trans[18*CC + l]), E19 = __expf(trans[19*CC + l]);

  const float* pb = probs + (size_t)b * TT * PR + l;

  float v = (s == 0) ? pb[0] * __expf(startv[l]) : 1.0f;

#define STEP(t) do {                                            \
    float pr = pb[(t) * PR];                                    \
    float a0, a1, a2, a3;                                       \
    a0  = __shfl(v, base + 0, 64) * E0;                         \
    a1  = __shfl(v, base + 1, 64) * E1;                         \
    a2  = __shfl(v, base + 2, 64) * E2;                         \
    a3  = __shfl(v, base + 3, 64) * E3;                         \
    a0 += __shfl(v, base + 4, 64) * E4;                         \
    a1 += __shfl(v, base + 5, 64) * E5;                         \
    a2 += __shfl(v, base + 6, 64) * E6;                         \
    a3 += __shfl(v, base + 7, 64) * E7;                         \
    a0 += __shfl(v, base + 8, 64) * E8;                         \
    a1 += __shfl(v, base + 9, 64) * E9;                         \
    a2 += __shfl(v, base + 10, 64) * E10;                       \
    a3 += __shfl(v, base + 11, 64) * E11;                       \
    a0 += __shfl(v, base + 12, 64) * E12;                       \
    a1 += __shfl(v, base + 13, 64) * E13;                       \
    a2 += __shfl(v, base + 14, 64) * E14;                       \
    a3 += __shfl(v, base + 15, 64) * E15;                       \
    a0 += __shfl(v, base + 16, 64) * E16;                       \
    a1 += __shfl(v, base + 17, 64) * E17;                       \
    a2 += __shfl(v, base + 18, 64) * E18;                       \
    a3 += __shfl(v, base + 19, 64) * E19;                       \
    v = ((a0 + a1) + (a2 + a3)) * pr;                           \
  } while (0)

  int nwarm = (s == 0 || empty) ? 0 : WW;
  for (int t = prod_start - nwarm; t < prod_start; ++t) STEP(t);

  __shared__ float sv[64];
  sv[tid] = v;
  __syncthreads();
  float Smid = 0.f;
  #pragma unroll
  for (int i = 0; i < CC; ++i) Smid += sv[base + i];
  __syncthreads();

  if (!empty) {
    for (int t = prod_start; t <= prod_end; ++t) STEP(t);
  }
#undef STEP

  sv[tid] = v;
  __syncthreads();
  float Send = 0.f;
  #pragma unroll
  for (int i = 0; i < CC; ++i) Send += sv[base + i];

  if (act) {
    float pz;
    if (empty)       pz = 0.f;
    else if (s == 0) pz = __logf(Send);               // includes initial mass
    else             pz = __logf(Send) - __logf(Smid);
    if (l == 0) partialZ[ch] = pz;
    if (!empty && s == (len - 2) / LL)
      finalA[b * CC + l] = v / Send;                  // normalized alpha at len-1
  }
}

// ---- Kernel B: coalesced gold sum + partialZ sum + final lse. ----
__global__ __launch_bounds__(64, 1) void combine_kernel(
    const float* __restrict__ probs, const float* __restrict__ partialZ,
    const float* __restrict__ finalA, const float* __restrict__ goldEmit,
    const int* __restrict__ seq_len, const float* __restrict__ startv,
    const float* __restrict__ endv, float* __restrict__ nll)
{
  int b = blockIdx.x;
  int j = threadIdx.x;
  int len = seq_len[b];

  float gsum = 0.f;
  const float* ge = goldEmit + ((size_t)b << 9);
  for (int t = j; t < len; t += 64) gsum += ge[t];
  gsum = wave_reduce_sum64(gsum);

  float Z;
  if (len == 1) {
    const float* pb = probs + (size_t)b * TT * PR;
    float val = (j < CC) ? __logf(pb[j]) + startv[j] + endv[j] : -INFINITY;
    float m = wave_reduce_max64(val);
    float ssum = wave_reduce_sum64((j < CC) ? __expf(val - m) : 0.f);
    Z = m + __logf(ssum);
  } else {
    float pz = (j < SS) ? partialZ[b * SS + j] : 0.f;
    pz = wave_reduce_sum64(pz);
    float ve = (j < CC) ? finalA[b * CC + j] * __expf(endv[j]) : 0.f;
    float ssum = wave_reduce_sum64(ve);
    Z = pz + __logf(ssum);
  }

  if (j == 0) nll[b] = Z - gsum;
}

// ---- Kernel C: mean over B (writes out directly; no memset needed) ----
__global__ __launch_bounds__(64) void mean_kernel(
    const float* __restrict__ nll, float* __restrict__ out)
{
  float v = nll[threadIdx.x];
  v = wave_reduce_sum64(v);
  if (threadIdx.x == 0) out[0] = v * (1.0f / BB);
}

extern "C" void kernel_launch(void* const* d_in, const int* in_sizes, int n_in,
                              void* d_out, int out_size, void* d_ws, size_t ws_size,
                              hipStream_t stream) {
  const int*   words   = (const int*)d_in[0];
  const int*   seq_len = (const int*)d_in[1];
  const int*   target  = (const int*)d_in[2];
  const float* emb     = (const float*)d_in[3];
  const float* ln_g    = (const float*)d_in[4];
  const float* ln_b    = (const float*)d_in[5];
  const float* W       = (const float*)d_in[6];
  const float* bias    = (const float*)d_in[7];
  const float* trans   = (const float*)d_in[8];
  const float* startv  = (const float*)d_in[9];
  const float* endv    = (const float*)d_in[10];

  float* probs    = (float*)d_ws;                          // 655,360 floats
  float* goldEmit = probs + (size_t)BB * TT * PR;          // 32,768
  float* partialZ = goldEmit + (size_t)BB * TT;            // 2,048
  float* finalA   = partialZ + NSEG;                       // 1,280
  float* nll      = finalA + BB * CC;                      // 64
  float* out      = (float*)d_out;

  token_probs_kernel<<<2048, 256, 0, stream>>>(words, emb, ln_g, ln_b, W, bias,
                                               seq_len, target, trans, startv,
                                               endv, probs, goldEmit);
  segment_kernel<<<(NSEG + 2) / 3, 64, 0, stream>>>(probs, seq_len, trans,
                                                    startv, partialZ, finalA);
  combine_kernel<<<BB, 64, 0, stream>>>(probs, partialZ, finalA, goldEmit,
                                        seq_len, startv, endv, nll);
  mean_kernel<<<1, 64, 0, stream>>>(nll, out);
}